// Round 1
// baseline (3248.927 us; speedup 1.0000x reference)
//
#include <hip/hip_runtime.h>
#include <hip/hip_bf16.h>

#define L_N 2
#define D_ 2048
#define H_ 16
#define DH_ 128
#define DFF_ 5504
#define B_ 4
#define S_ 1000
#define C_ 7
#define T_ 45
#define M_ 4000   // B_*S_

typedef short bf16x8 __attribute__((ext_vector_type(8)));
typedef float f32x4 __attribute__((ext_vector_type(4)));

__constant__ float NF4_TAB[16] = {
  -1.0f, -0.6961928009986877f, -0.5250730514526367f, -0.39491748809814453f,
  -0.28444138169288635f, -0.18477343022823334f, -0.09105003625154495f, 0.0f,
  0.07958029955625534f, 0.16093020141124725f, 0.24611230194568634f,
  0.3379152417182922f, 0.44070982933044434f, 0.5626170039176941f,
  0.7229568362236023f, 1.0f };

__device__ __forceinline__ unsigned short f2bf(float f) {
  unsigned int u = __float_as_uint(f);
  u += 0x7fffu + ((u >> 16) & 1u);          // RNE
  return (unsigned short)(u >> 16);
}
__device__ __forceinline__ float bf2f(unsigned short u) {
  return __uint_as_float(((unsigned int)u) << 16);
}
__device__ __forceinline__ f32x4 zero4() { f32x4 z; z[0]=0.f; z[1]=0.f; z[2]=0.f; z[3]=0.f; return z; }
__device__ __forceinline__ f32x4 mfma16(bf16x8 a, bf16x8 b, f32x4 c) {
  return __builtin_amdgcn_mfma_f32_16x16x32_bf16(a, b, c, 0, 0, 0);
}

// ---------------- rope tables ----------------
__global__ void rope_tables(float* __restrict__ cosT, float* __restrict__ sinT) {
  int s = blockIdx.x, d = threadIdx.x;   // 128 threads
  int j = d & 63;
  float inv = expf(-(float)j * (9.210340371976184f / 64.f)); // 10000^(-j/64)
  float ang = (float)s * inv;
  cosT[s * DH_ + d] = cosf(ang);
  sinT[s * DH_ + d] = sinf(ang);
}

// ---------------- embedding gather ----------------
__global__ __launch_bounds__(256) void embed_gather(const int* __restrict__ tok,
    const float* __restrict__ emb, float* __restrict__ h) {
  int row = blockIdx.x;                 // 0..3999  (b*S+s)
  int tk = tok[row];
  const float4* src = reinterpret_cast<const float4*>(emb + (size_t)tk * D_);
  float4* dst = reinterpret_cast<float4*>(h + (size_t)row * D_);
  dst[threadIdx.x] = src[threadIdx.x];
  dst[threadIdx.x + 256] = src[threadIdx.x + 256];
}

// ---------------- rmsnorm: fp32 in -> bf16 out ----------------
__global__ __launch_bounds__(256) void rmsnorm_k(const float* __restrict__ h,
    const float* __restrict__ w, unsigned short* __restrict__ out) {
  const int row = blockIdx.x, t = threadIdx.x;
  const float* hp = h + (size_t)row * D_;
  float4 a = *reinterpret_cast<const float4*>(&hp[t * 8]);
  float4 b = *reinterpret_cast<const float4*>(&hp[t * 8 + 4]);
  float ss = a.x*a.x + a.y*a.y + a.z*a.z + a.w*a.w
           + b.x*b.x + b.y*b.y + b.z*b.z + b.w*b.w;
#pragma unroll
  for (int m = 1; m < 64; m <<= 1) ss += __shfl_xor(ss, m);
  __shared__ float red[4];
  if ((t & 63) == 0) red[t >> 6] = ss;
  __syncthreads();
  float tot = red[0] + red[1] + red[2] + red[3];
  float rs = rsqrtf(tot * (1.0f / D_) + 1e-5f);
  float4 wa = *reinterpret_cast<const float4*>(&w[t * 8]);
  float4 wb = *reinterpret_cast<const float4*>(&w[t * 8 + 4]);
  unsigned r0 = (unsigned)f2bf(a.x*rs*wa.x) | ((unsigned)f2bf(a.y*rs*wa.y) << 16);
  unsigned r1 = (unsigned)f2bf(a.z*rs*wa.z) | ((unsigned)f2bf(a.w*rs*wa.w) << 16);
  unsigned r2 = (unsigned)f2bf(b.x*rs*wb.x) | ((unsigned)f2bf(b.y*rs*wb.y) << 16);
  unsigned r3 = (unsigned)f2bf(b.z*rs*wb.z) | ((unsigned)f2bf(b.w*rs*wb.w) << 16);
  int4 ov; ov.x = (int)r0; ov.y = (int)r1; ov.z = (int)r2; ov.w = (int)r3;
  *reinterpret_cast<int4*>(&out[(size_t)row * D_ + t * 8]) = ov;
}

// ---------------- NF4 dequant GEMM: C[M][N] = A[M][K](bf16) @ W[N][K]^T ----------------
// MODE 0: out bf16 [M][N]
// MODE 1: out bf16 q/k/v layout [B][H][S][DH]
// MODE 2: out bf16 [M][N] = silu(gin) * acc
// MODE 3: out fp32 [M][N] += acc   (residual)
template<int MODE>
__global__ __launch_bounds__(256) void gemm_nf4(
    const unsigned short* __restrict__ A,
    const int* __restrict__ Widx,
    const float* __restrict__ Wsc,
    int Mdim, int N, int K,
    void* outp,
    const unsigned short* gin) {
  __shared__ unsigned short A_lds[128][72];
  __shared__ unsigned short B_lds[128][72];
  __shared__ float nf4[16];
  const int t = threadIdx.x;
  if (t < 16) nf4[t] = NF4_TAB[t];
  const int n0 = blockIdx.x * 128;
  const int m0 = blockIdx.y * 128;
  const int lane = t & 63, wid = t >> 6;
  const int wm = (wid >> 1) * 64, wn = (wid & 1) * 64;
  const int lr = lane & 15, lg = lane >> 4;
  const int KB = K >> 6;

  f32x4 acc[4][4];
#pragma unroll
  for (int i = 0; i < 4; ++i)
#pragma unroll
    for (int j = 0; j < 4; ++j) acc[i][j] = zero4();

  const int kT = K >> 6;
  for (int kt = 0; kt < kT; ++kt) {
    __syncthreads();
    // stage A tile 128x64 (bf16 copy)
#pragma unroll
    for (int j = 0; j < 4; ++j) {
      int q = t + 256 * j;
      int row = q >> 3, c8 = (q & 7) << 3;
      int gm = m0 + row;
      int4 v; v.x = 0; v.y = 0; v.z = 0; v.w = 0;
      if (gm < Mdim) v = *reinterpret_cast<const int4*>(&A[(size_t)gm * K + kt * 64 + c8]);
      *reinterpret_cast<int4*>(&A_lds[row][c8]) = v;
    }
    // stage B tile 128x64 with NF4 dequant
#pragma unroll
    for (int j = 0; j < 8; ++j) {
      int q = t + 256 * j;
      int row = q >> 4, c4 = (q & 15) << 2;
      int gn = n0 + row;
      int4 iv = *reinterpret_cast<const int4*>(&Widx[(size_t)gn * K + kt * 64 + c4]);
      float sc = Wsc[(size_t)gn * KB + kt];
      ushort4 o;
      o.x = f2bf(nf4[iv.x & 15] * sc);
      o.y = f2bf(nf4[iv.y & 15] * sc);
      o.z = f2bf(nf4[iv.z & 15] * sc);
      o.w = f2bf(nf4[iv.w & 15] * sc);
      *reinterpret_cast<ushort4*>(&B_lds[row][c4]) = o;
    }
    __syncthreads();
#pragma unroll
    for (int ks = 0; ks < 2; ++ks) {
      bf16x8 af[4], bfr[4];
#pragma unroll
      for (int i = 0; i < 4; ++i) {
        af[i]  = *reinterpret_cast<const bf16x8*>(&A_lds[wm + i * 16 + lr][ks * 32 + lg * 8]);
        bfr[i] = *reinterpret_cast<const bf16x8*>(&B_lds[wn + i * 16 + lr][ks * 32 + lg * 8]);
      }
#pragma unroll
      for (int mi = 0; mi < 4; ++mi)
#pragma unroll
        for (int ni = 0; ni < 4; ++ni)
          acc[mi][ni] = mfma16(af[mi], bfr[ni], acc[mi][ni]);
    }
  }

  // epilogue: C row = m0+wm+mi*16+lg*4+r, col = n0+wn+ni*16+lr
#pragma unroll
  for (int mi = 0; mi < 4; ++mi) {
#pragma unroll
    for (int r = 0; r < 4; ++r) {
      int gm = m0 + wm + mi * 16 + lg * 4 + r;
      if (gm >= Mdim) continue;
#pragma unroll
      for (int ni = 0; ni < 4; ++ni) {
        int gn = n0 + wn + ni * 16 + lr;
        float v = acc[mi][ni][r];
        if (MODE == 0) {
          ((unsigned short*)outp)[(size_t)gm * N + gn] = f2bf(v);
        } else if (MODE == 1) {
          int b = gm / S_, s = gm - b * S_;
          int hh = gn >> 7, d = gn & 127;
          ((unsigned short*)outp)[(((size_t)(b * H_ + hh) * S_ + s) << 7) + d] = f2bf(v);
        } else if (MODE == 2) {
          float g = bf2f(gin[(size_t)gm * N + gn]);
          float sg = g / (1.f + __expf(-g));
          ((unsigned short*)outp)[(size_t)gm * N + gn] = f2bf(sg * v);
        } else {
          ((float*)outp)[(size_t)gm * N + gn] += v;
        }
      }
    }
  }
}

// ---------------- rope apply (in-place, q & k) ----------------
__global__ __launch_bounds__(256) void rope_apply(unsigned short* __restrict__ qb,
    unsigned short* __restrict__ kb, const float* __restrict__ cosT,
    const float* __restrict__ sinT) {
  size_t i = (size_t)blockIdx.x * 256 + threadIdx.x;  // B*H*S*64 slots
  int d = (int)(i & 63);
  size_t row = i >> 6;              // (b*H+h)*S + s
  int s = (int)(row % S_);
  size_t base = row * DH_;
  float c = cosT[s * DH_ + d], sn = sinT[s * DH_ + d];
  float q0 = bf2f(qb[base + d]), q1 = bf2f(qb[base + d + 64]);
  qb[base + d]      = f2bf(q0 * c - q1 * sn);
  qb[base + d + 64] = f2bf(q1 * c + q0 * sn);
  float k0 = bf2f(kb[base + d]), k1 = bf2f(kb[base + d + 64]);
  kb[base + d]      = f2bf(k0 * c - k1 * sn);
  kb[base + d + 64] = f2bf(k1 * c + k0 * sn);
}

// ---------------- causal flash attention ----------------
// grid (16, B*H); block 256 = 4 waves; each wave owns 16 q rows; kv tiles of 64
__global__ __launch_bounds__(256) void attn_k(const unsigned short* __restrict__ qg,
    const unsigned short* __restrict__ kg, const unsigned short* __restrict__ vg,
    unsigned short* __restrict__ ctx) {
  __shared__ unsigned short K_lds[64][136];
  __shared__ unsigned short VT_lds[128][72];
  __shared__ unsigned short P_lds[64][72];
  const int t = threadIdx.x, lane = t & 63, w = t >> 6;
  const int lr = lane & 15, lg = lane >> 4;
  const int qt = blockIdx.x, bh = blockIdx.y;
  const int q0 = qt * 64;
  const size_t base = (size_t)bh * S_ * DH_;
  const int qrow = q0 + w * 16 + lr;

  bf16x8 qf[4];
#pragma unroll
  for (int ks = 0; ks < 4; ++ks) {
    bf16x8 z; 
#pragma unroll
    for (int e = 0; e < 8; ++e) z[e] = 0;
    if (qrow < S_) z = *reinterpret_cast<const bf16x8*>(&qg[base + (size_t)qrow * DH_ + ks * 32 + lg * 8]);
    qf[ks] = z;
  }
  float mst[4], lst[4];
  f32x4 cacc[8];
#pragma unroll
  for (int r = 0; r < 4; ++r) { mst[r] = -1e30f; lst[r] = 0.f; }
#pragma unroll
  for (int f = 0; f < 8; ++f) cacc[f] = zero4();

  for (int kt = 0; kt <= qt; ++kt) {
    const int kv0 = kt * 64;
    __syncthreads();
    // stage K [64][128]
#pragma unroll
    for (int j = 0; j < 4; ++j) {
      int qq = t + 256 * j;
      int row = qq >> 4, c8 = (qq & 15) << 3;
      int4 v; v.x = 0; v.y = 0; v.z = 0; v.w = 0;
      if (kv0 + row < S_) v = *reinterpret_cast<const int4*>(&kg[base + (size_t)(kv0 + row) * DH_ + c8]);
      *reinterpret_cast<int4*>(&K_lds[row][c8]) = v;
    }
    // stage V transposed [128][64]
#pragma unroll
    for (int j = 0; j < 4; ++j) {
      int qq = t + 256 * j;
      int row = qq >> 4, c8 = (qq & 15) << 3;
      int4 v; v.x = 0; v.y = 0; v.z = 0; v.w = 0;
      if (kv0 + row < S_) v = *reinterpret_cast<const int4*>(&vg[base + (size_t)(kv0 + row) * DH_ + c8]);
      unsigned ux;
      ux = (unsigned)v.x; VT_lds[c8 + 0][row] = ux & 0xffff; VT_lds[c8 + 1][row] = ux >> 16;
      ux = (unsigned)v.y; VT_lds[c8 + 2][row] = ux & 0xffff; VT_lds[c8 + 3][row] = ux >> 16;
      ux = (unsigned)v.z; VT_lds[c8 + 4][row] = ux & 0xffff; VT_lds[c8 + 5][row] = ux >> 16;
      ux = (unsigned)v.w; VT_lds[c8 + 6][row] = ux & 0xffff; VT_lds[c8 + 7][row] = ux >> 16;
    }
    __syncthreads();

    // QK^T: 16 q-rows x 64 kv
    f32x4 sacc[4];
#pragma unroll
    for (int c = 0; c < 4; ++c) sacc[c] = zero4();
#pragma unroll
    for (int ks = 0; ks < 4; ++ks) {
#pragma unroll
      for (int c = 0; c < 4; ++c) {
        bf16x8 kf = *reinterpret_cast<const bf16x8*>(&K_lds[c * 16 + lr][ks * 32 + lg * 8]);
        sacc[c] = mfma16(qf[ks], kf, sacc[c]);
      }
    }
    // scale + causal mask
    float sc[4][4], mx[4];
#pragma unroll
    for (int r = 0; r < 4; ++r) mx[r] = -1e30f;
#pragma unroll
    for (int c = 0; c < 4; ++c) {
      int col = kv0 + c * 16 + lr;
#pragma unroll
      for (int r = 0; r < 4; ++r) {
        int rowq = q0 + w * 16 + lg * 4 + r;
        float v = sacc[c][r] * 0.08838834764831845f;  // 1/sqrt(128)
        if (col > rowq || col >= S_) v = -1e30f;
        sc[c][r] = v;
        mx[r] = fmaxf(mx[r], v);
      }
    }
    // row reduce over the 16-lane group
#pragma unroll
    for (int m = 1; m < 16; m <<= 1)
#pragma unroll
      for (int r = 0; r < 4; ++r) mx[r] = fmaxf(mx[r], __shfl_xor(mx[r], m));
    float corr[4], rsm[4];
#pragma unroll
    for (int r = 0; r < 4; ++r) {
      float mn = fmaxf(mst[r], mx[r]);
      corr[r] = __expf(mst[r] - mn);
      mst[r] = mn;
      float s = 0.f;
#pragma unroll
      for (int c = 0; c < 4; ++c) { float p = __expf(sc[c][r] - mn); sc[c][r] = p; s += p; }
      rsm[r] = s;
    }
#pragma unroll
    for (int m = 1; m < 16; m <<= 1)
#pragma unroll
      for (int r = 0; r < 4; ++r) rsm[r] += __shfl_xor(rsm[r], m);
#pragma unroll
    for (int r = 0; r < 4; ++r) lst[r] = lst[r] * corr[r] + rsm[r];
#pragma unroll
    for (int f = 0; f < 8; ++f)
#pragma unroll
      for (int r = 0; r < 4; ++r) cacc[f][r] *= corr[r];
    // P -> LDS (bf16)
#pragma unroll
    for (int c = 0; c < 4; ++c)
#pragma unroll
      for (int r = 0; r < 4; ++r)
        P_lds[w * 16 + lg * 4 + r][c * 16 + lr] = f2bf(sc[c][r]);
    __syncthreads();
    // PV
#pragma unroll
    for (int ks = 0; ks < 2; ++ks) {
      bf16x8 pf = *reinterpret_cast<const bf16x8*>(&P_lds[w * 16 + lr][ks * 32 + lg * 8]);
#pragma unroll
      for (int f = 0; f < 8; ++f) {
        bf16x8 vf = *reinterpret_cast<const bf16x8*>(&VT_lds[f * 16 + lr][ks * 32 + lg * 8]);
        cacc[f] = mfma16(pf, vf, cacc[f]);
      }
    }
  }
  // write ctx [b][s][h*128+d] bf16
  const int b = bh >> 4, hh = bh & 15;
  float inv[4];
#pragma unroll
  for (int r = 0; r < 4; ++r) inv[r] = 1.f / lst[r];
#pragma unroll
  for (int f = 0; f < 8; ++f)
#pragma unroll
    for (int r = 0; r < 4; ++r) {
      int qgl = q0 + w * 16 + lg * 4 + r;
      if (qgl < S_)
        ctx[((size_t)(b * S_ + qgl)) * D_ + hh * DH_ + f * 16 + lr] = f2bf(cacc[f][r] * inv[r]);
    }
}

// ---------------- mean pool over sequence ----------------
__global__ __launch_bounds__(256) void meanpool(const unsigned short* __restrict__ xn,
    float* __restrict__ out) {
  int d = blockIdx.x * 256 + threadIdx.x;
  int b = blockIdx.y;
  const unsigned short* p = xn + (size_t)b * S_ * D_ + d;
  float s = 0.f;
  for (int i = 0; i < S_; ++i) s += bf2f(p[(size_t)i * D_]);
  out[(size_t)b * D_ + d] = s * (1.f / S_);
}

// ---------------- series branch: adds into out ----------------
__global__ __launch_bounds__(256) void series_k(const float* __restrict__ x,
    const float* __restrict__ pw, const float* __restrict__ pb, float* out) {
  __shared__ float sm[T_];
  __shared__ float emb[D_];
  __shared__ float red[4];
  int b = blockIdx.x, t = threadIdx.x;
  if (t < T_) {
    float s = 0.f;
    for (int c = 0; c < C_; ++c) s += x[((size_t)b * C_ + c) * T_ + t];
    sm[t] = s * (1.f / C_);
  }
  __syncthreads();
  float ssq = 0.f;
#pragma unroll
  for (int j = 0; j < D_ / 256; ++j) {
    int d = j * 256 + t;
    float e = pb[d];
    for (int tt = 0; tt < T_; ++tt) e += sm[tt] * pw[(size_t)d * T_ + tt];
    emb[d] = e;
    ssq += e * e;
  }
#pragma unroll
  for (int m = 1; m < 64; m <<= 1) ssq += __shfl_xor(ssq, m);
  if ((t & 63) == 0) red[t >> 6] = ssq;
  __syncthreads();
  float tot = red[0] + red[1] + red[2] + red[3];
  float inv = 1.f / fmaxf(sqrtf(tot), 1e-12f);
#pragma unroll
  for (int j = 0; j < D_ / 256; ++j) {
    int d = j * 256 + t;
    out[(size_t)b * D_ + d] += emb[d] * inv;
  }
}

extern "C" void kernel_launch(void* const* d_in, const int* in_sizes, int n_in,
                              void* d_out, int out_size, void* d_ws, size_t ws_size,
                              hipStream_t stream) {
  const float* x      = (const float*)d_in[0];
  const int*   tok    = (const int*)d_in[1];
  const float* embedw = (const float*)d_in[2];
  const int*   wq_idx = (const int*)d_in[3];
  const float* wq_sc  = (const float*)d_in[4];
  const int*   wk_idx = (const int*)d_in[5];
  const float* wk_sc  = (const float*)d_in[6];
  const int*   wv_idx = (const int*)d_in[7];
  const float* wv_sc  = (const float*)d_in[8];
  const int*   wo_idx = (const int*)d_in[9];
  const float* wo_sc  = (const float*)d_in[10];
  const int*   wg_idx = (const int*)d_in[11];
  const float* wg_sc  = (const float*)d_in[12];
  const int*   wu_idx = (const int*)d_in[13];
  const float* wu_sc  = (const float*)d_in[14];
  const int*   wd_idx = (const int*)d_in[15];
  const float* wd_sc  = (const float*)d_in[16];
  const float* ln1    = (const float*)d_in[17];
  const float* ln2    = (const float*)d_in[18];
  const float* lnf    = (const float*)d_in[19];
  const float* projw  = (const float*)d_in[20];
  const float* projb  = (const float*)d_in[21];
  float* out = (float*)d_out;
  (void)in_sizes; (void)n_in; (void)out_size; (void)ws_size;

  char* wsp = (char*)d_ws;
  size_t off = 0;
  auto alloc = [&](size_t bytes) -> void* {
    void* p = wsp + off; off += (bytes + 255) & ~(size_t)255; return p; };
  float* cosT = (float*)alloc((size_t)S_ * DH_ * 4);
  float* sinT = (float*)alloc((size_t)S_ * DH_ * 4);
  float* hbuf = (float*)alloc((size_t)M_ * D_ * 4);
  unsigned short* xn  = (unsigned short*)alloc((size_t)M_ * D_ * 2);
  unsigned short* qb  = (unsigned short*)alloc((size_t)B_ * H_ * S_ * DH_ * 2);
  unsigned short* kb  = (unsigned short*)alloc((size_t)B_ * H_ * S_ * DH_ * 2);
  unsigned short* vb  = (unsigned short*)alloc((size_t)B_ * H_ * S_ * DH_ * 2);
  unsigned short* ctx = xn;     // alias: xn dead during attention, rewritten after O-GEMM
  unsigned short* gbuf = qb;    // alias: 44MB g/act spans q+k+v (49MB), dead during MLP

  rope_tables<<<S_, DH_, 0, stream>>>(cosT, sinT);
  embed_gather<<<M_, 256, 0, stream>>>(tok, embedw, hbuf);

  const dim3 gAtt(D_ / 128, (M_ + 127) / 128);    // (16, 32)
  const dim3 gMlp(DFF_ / 128, (M_ + 127) / 128);  // (43, 32)

  for (int l = 0; l < L_N; ++l) {
    const int*   wqi = wq_idx + (size_t)l * D_ * D_;
    const float* wqs = wq_sc + (size_t)l * D_ * (D_ / 64);
    const int*   wki = wk_idx + (size_t)l * D_ * D_;
    const float* wks = wk_sc + (size_t)l * D_ * (D_ / 64);
    const int*   wvi = wv_idx + (size_t)l * D_ * D_;
    const float* wvs = wv_sc + (size_t)l * D_ * (D_ / 64);
    const int*   woi = wo_idx + (size_t)l * D_ * D_;
    const float* wos = wo_sc + (size_t)l * D_ * (D_ / 64);
    const int*   wgi = wg_idx + (size_t)l * DFF_ * D_;
    const float* wgs = wg_sc + (size_t)l * DFF_ * (D_ / 64);
    const int*   wui = wu_idx + (size_t)l * DFF_ * D_;
    const float* wus = wu_sc + (size_t)l * DFF_ * (D_ / 64);
    const int*   wdi = wd_idx + (size_t)l * D_ * DFF_;
    const float* wds = wd_sc + (size_t)l * D_ * (DFF_ / 64);

    rmsnorm_k<<<M_, 256, 0, stream>>>(hbuf, ln1 + l * D_, xn);
    gemm_nf4<1><<<gAtt, 256, 0, stream>>>(xn, wqi, wqs, M_, D_, D_, qb, nullptr);
    gemm_nf4<1><<<gAtt, 256, 0, stream>>>(xn, wki, wks, M_, D_, D_, kb, nullptr);
    gemm_nf4<1><<<gAtt, 256, 0, stream>>>(xn, wvi, wvs, M_, D_, D_, vb, nullptr);
    rope_apply<<<(B_ * H_ * S_ * 64) / 256, 256, 0, stream>>>(qb, kb, cosT, sinT);
    attn_k<<<dim3(16, B_ * H_), 256, 0, stream>>>(qb, kb, vb, ctx);
    gemm_nf4<3><<<gAtt, 256, 0, stream>>>(ctx, woi, wos, M_, D_, D_, hbuf, nullptr);
    rmsnorm_k<<<M_, 256, 0, stream>>>(hbuf, ln2 + l * D_, xn);
    gemm_nf4<0><<<gMlp, 256, 0, stream>>>(xn, wgi, wgs, M_, DFF_, D_, gbuf, nullptr);
    gemm_nf4<2><<<gMlp, 256, 0, stream>>>(xn, wui, wus, M_, DFF_, D_, gbuf, gbuf);
    gemm_nf4<3><<<gAtt, 256, 0, stream>>>(gbuf, wdi, wds, M_, D_, DFF_, hbuf, nullptr);
  }

  rmsnorm_k<<<M_, 256, 0, stream>>>(hbuf, lnf, xn);
  meanpool<<<dim3(D_ / 256, B_), 256, 0, stream>>>(xn, out);
  series_k<<<B_, 256, 0, stream>>>(x, projw, projb, out);
}

// Round 2
// 2060.183 us; speedup vs baseline: 1.5770x; 1.5770x over previous
//
#include <hip/hip_runtime.h>
#include <hip/hip_bf16.h>

#define L_N 2
#define D_ 2048
#define H_ 16
#define DH_ 128
#define DFF_ 5504
#define B_ 4
#define S_ 1000
#define C_ 7
#define T_ 45
#define M_ 4000   // B_*S_

typedef short bf16x8 __attribute__((ext_vector_type(8)));
typedef float f32x4 __attribute__((ext_vector_type(4)));

__constant__ float NF4_TAB[16] = {
  -1.0f, -0.6961928009986877f, -0.5250730514526367f, -0.39491748809814453f,
  -0.28444138169288635f, -0.18477343022823334f, -0.09105003625154495f, 0.0f,
  0.07958029955625534f, 0.16093020141124725f, 0.24611230194568634f,
  0.3379152417182922f, 0.44070982933044434f, 0.5626170039176941f,
  0.7229568362236023f, 1.0f };

__device__ __forceinline__ unsigned short f2bf(float f) {
  unsigned int u = __float_as_uint(f);
  u += 0x7fffu + ((u >> 16) & 1u);          // RNE
  return (unsigned short)(u >> 16);
}
__device__ __forceinline__ float bf2f(unsigned short u) {
  return __uint_as_float(((unsigned int)u) << 16);
}
__device__ __forceinline__ f32x4 zero4() { f32x4 z; z[0]=0.f; z[1]=0.f; z[2]=0.f; z[3]=0.f; return z; }
__device__ __forceinline__ f32x4 mfma16(bf16x8 a, bf16x8 b, f32x4 c) {
  return __builtin_amdgcn_mfma_f32_16x16x32_bf16(a, b, c, 0, 0, 0);
}

typedef __attribute__((address_space(3))) unsigned int lds_u32;
typedef const __attribute__((address_space(1))) unsigned int glb_u32;
__device__ __forceinline__ void gload16(const void* g, void* l) {
  __builtin_amdgcn_global_load_lds((glb_u32*)g, (lds_u32*)l, 16, 0, 0);
}

// ---------------- rope tables ----------------
__global__ void rope_tables(float* __restrict__ cosT, float* __restrict__ sinT) {
  int s = blockIdx.x, d = threadIdx.x;   // 128 threads
  int j = d & 63;
  float inv = expf(-(float)j * (9.210340371976184f / 64.f)); // 10000^(-j/64)
  float ang = (float)s * inv;
  cosT[s * DH_ + d] = cosf(ang);
  sinT[s * DH_ + d] = sinf(ang);
}

// ---------------- embedding gather ----------------
__global__ __launch_bounds__(256) void embed_gather(const int* __restrict__ tok,
    const float* __restrict__ emb, float* __restrict__ h) {
  int row = blockIdx.x;                 // 0..3999  (b*S+s)
  int tk = tok[row];
  const float4* src = reinterpret_cast<const float4*>(emb + (size_t)tk * D_);
  float4* dst = reinterpret_cast<float4*>(h + (size_t)row * D_);
  dst[threadIdx.x] = src[threadIdx.x];
  dst[threadIdx.x + 256] = src[threadIdx.x + 256];
}

// ---------------- rmsnorm: fp32 in -> bf16 out ----------------
__global__ __launch_bounds__(256) void rmsnorm_k(const float* __restrict__ h,
    const float* __restrict__ w, unsigned short* __restrict__ out) {
  const int row = blockIdx.x, t = threadIdx.x;
  const float* hp = h + (size_t)row * D_;
  float4 a = *reinterpret_cast<const float4*>(&hp[t * 8]);
  float4 b = *reinterpret_cast<const float4*>(&hp[t * 8 + 4]);
  float ss = a.x*a.x + a.y*a.y + a.z*a.z + a.w*a.w
           + b.x*b.x + b.y*b.y + b.z*b.z + b.w*b.w;
#pragma unroll
  for (int m = 1; m < 64; m <<= 1) ss += __shfl_xor(ss, m);
  __shared__ float red[4];
  if ((t & 63) == 0) red[t >> 6] = ss;
  __syncthreads();
  float tot = red[0] + red[1] + red[2] + red[3];
  float rs = rsqrtf(tot * (1.0f / D_) + 1e-5f);
  float4 wa = *reinterpret_cast<const float4*>(&w[t * 8]);
  float4 wb = *reinterpret_cast<const float4*>(&w[t * 8 + 4]);
  unsigned r0 = (unsigned)f2bf(a.x*rs*wa.x) | ((unsigned)f2bf(a.y*rs*wa.y) << 16);
  unsigned r1 = (unsigned)f2bf(a.z*rs*wa.z) | ((unsigned)f2bf(a.w*rs*wa.w) << 16);
  unsigned r2 = (unsigned)f2bf(b.x*rs*wb.x) | ((unsigned)f2bf(b.y*rs*wb.y) << 16);
  unsigned r3 = (unsigned)f2bf(b.z*rs*wb.z) | ((unsigned)f2bf(b.w*rs*wb.w) << 16);
  int4 ov; ov.x = (int)r0; ov.y = (int)r1; ov.z = (int)r2; ov.w = (int)r3;
  *reinterpret_cast<int4*>(&out[(size_t)row * D_ + t * 8]) = ov;
}

// ---------------- NF4 dequant: idx int32 [N][K] + scale -> bf16 [N][K] ----------------
__global__ __launch_bounds__(256) void dequant_k(const int* __restrict__ idx,
    const float* __restrict__ sc, unsigned short* __restrict__ out, int K) {
  __shared__ float nf4[16];
  const int t = threadIdx.x;
  if (t < 16) nf4[t] = NF4_TAB[t];
  __syncthreads();
  const int row = blockIdx.y;
  const int k0 = blockIdx.x * 2048 + t * 8;
  if (k0 >= K) return;
  const size_t base = (size_t)row * K + k0;
  int4 a = *reinterpret_cast<const int4*>(&idx[base]);
  int4 b = *reinterpret_cast<const int4*>(&idx[base + 4]);
  float s = sc[(size_t)row * (K >> 6) + (k0 >> 6)];
  unsigned r0 = (unsigned)f2bf(nf4[a.x & 15] * s) | ((unsigned)f2bf(nf4[a.y & 15] * s) << 16);
  unsigned r1 = (unsigned)f2bf(nf4[a.z & 15] * s) | ((unsigned)f2bf(nf4[a.w & 15] * s) << 16);
  unsigned r2 = (unsigned)f2bf(nf4[b.x & 15] * s) | ((unsigned)f2bf(nf4[b.y & 15] * s) << 16);
  unsigned r3 = (unsigned)f2bf(nf4[b.z & 15] * s) | ((unsigned)f2bf(nf4[b.w & 15] * s) << 16);
  int4 ov; ov.x = (int)r0; ov.y = (int)r1; ov.z = (int)r2; ov.w = (int)r3;
  *reinterpret_cast<int4*>(&out[base]) = ov;
}

// ---------------- bf16 GEMM (m97 structure): C[M][N] = A[M][K] @ W[N][K]^T ----------------
// MODE 0: out bf16 [M][N]
// MODE 1: out bf16 q/k/v layout [B][H][S][DH]
// MODE 2: out bf16 [M][N] = silu(gin) * acc
// MODE 3: out fp32 [M][N] += acc   (residual)
template<int MODE>
__global__ __launch_bounds__(256) void gemm_bf16(
    const unsigned short* __restrict__ A,
    const unsigned short* __restrict__ Bw,
    int Mdim, int N, int K, int nx,
    void* outp, const unsigned short* gin) {
  __shared__ unsigned short A_lds[128 * 64];
  __shared__ unsigned short B_lds[128 * 64];
  const int t = threadIdx.x;
  const int lane = t & 63, wid = t >> 6;

  // bijective XCD swizzle (gridDim.x % 8 == 0 for all our launches)
  const int nwg = gridDim.x;
  const int bid = blockIdx.x;
  const int wg = (bid & 7) * (nwg >> 3) + (bid >> 3);
  const int n0 = (wg % nx) * 128;
  const int m0 = (wg / nx) * 128;

  const int wm = (wid >> 1) * 64, wn = (wid & 1) * 64;
  const int lr = lane & 15, lg = lane >> 4;
  // staging decomposition: chunk = 1024B = 8 rows x 128B; lane covers 16B
  const int lrow = lane >> 3;
  const int lcolb = (lane & 7) << 4;   // byte offset within row

  f32x4 acc[4][4];
#pragma unroll
  for (int i = 0; i < 4; ++i)
#pragma unroll
    for (int j = 0; j < 4; ++j) acc[i][j] = zero4();

  const int kT = K >> 6;
  for (int kt = 0; kt < kT; ++kt) {
    // stage A and B tiles via async global->LDS, 16B per lane
#pragma unroll
    for (int c0 = 0; c0 < 4; ++c0) {
      const int c = wid + 4 * c0;
      int gr = m0 + c * 8 + lrow;
      gr = gr < Mdim ? gr : Mdim - 1;          // clamp: OOB rows discarded in epilogue
      gload16((const char*)A + ((size_t)gr * K + kt * 64) * 2 + lcolb,
              (char*)A_lds + c * 1024);
      const int nr = n0 + c * 8 + lrow;        // always in-bounds (N % 128 == 0)
      gload16((const char*)Bw + ((size_t)nr * K + kt * 64) * 2 + lcolb,
              (char*)B_lds + c * 1024);
    }
    __syncthreads();
#pragma unroll
    for (int ks = 0; ks < 2; ++ks) {
      bf16x8 af[4], bfr[4];
#pragma unroll
      for (int i = 0; i < 4; ++i) {
        af[i]  = *reinterpret_cast<const bf16x8*>(&A_lds[(wm + i * 16 + lr) * 64 + ks * 32 + lg * 8]);
        bfr[i] = *reinterpret_cast<const bf16x8*>(&B_lds[(wn + i * 16 + lr) * 64 + ks * 32 + lg * 8]);
      }
#pragma unroll
      for (int mi = 0; mi < 4; ++mi)
#pragma unroll
        for (int ni = 0; ni < 4; ++ni)
          acc[mi][ni] = mfma16(af[mi], bfr[ni], acc[mi][ni]);
    }
    __syncthreads();
  }

  // epilogue: C row = m0+wm+mi*16+lg*4+r, col = n0+wn+ni*16+lr
#pragma unroll
  for (int mi = 0; mi < 4; ++mi) {
#pragma unroll
    for (int r = 0; r < 4; ++r) {
      int gm = m0 + wm + mi * 16 + lg * 4 + r;
      if (gm >= Mdim) continue;
#pragma unroll
      for (int ni = 0; ni < 4; ++ni) {
        int gn = n0 + wn + ni * 16 + lr;
        float v = acc[mi][ni][r];
        if (MODE == 0) {
          ((unsigned short*)outp)[(size_t)gm * N + gn] = f2bf(v);
        } else if (MODE == 1) {
          int b = gm / S_, s = gm - b * S_;
          int hh = gn >> 7, d = gn & 127;
          ((unsigned short*)outp)[(((size_t)(b * H_ + hh) * S_ + s) << 7) + d] = f2bf(v);
        } else if (MODE == 2) {
          float g = bf2f(gin[(size_t)gm * N + gn]);
          float sg = g / (1.f + __expf(-g));
          ((unsigned short*)outp)[(size_t)gm * N + gn] = f2bf(sg * v);
        } else {
          ((float*)outp)[(size_t)gm * N + gn] += v;
        }
      }
    }
  }
}

// ---------------- rope apply (in-place, q & k) ----------------
__global__ __launch_bounds__(256) void rope_apply(unsigned short* __restrict__ qb,
    unsigned short* __restrict__ kb, const float* __restrict__ cosT,
    const float* __restrict__ sinT) {
  size_t i = (size_t)blockIdx.x * 256 + threadIdx.x;  // B*H*S*64 slots
  int d = (int)(i & 63);
  size_t row = i >> 6;              // (b*H+h)*S + s
  int s = (int)(row % S_);
  size_t base = row * DH_;
  float c = cosT[s * DH_ + d], sn = sinT[s * DH_ + d];
  float q0 = bf2f(qb[base + d]), q1 = bf2f(qb[base + d + 64]);
  qb[base + d]      = f2bf(q0 * c - q1 * sn);
  qb[base + d + 64] = f2bf(q1 * c + q0 * sn);
  float k0 = bf2f(kb[base + d]), k1 = bf2f(kb[base + d + 64]);
  kb[base + d]      = f2bf(k0 * c - k1 * sn);
  kb[base + d + 64] = f2bf(k1 * c + k0 * sn);
}

// ---------------- causal flash attention ----------------
// grid (16, B*H); block 256 = 4 waves; each wave owns 16 q rows; kv tiles of 64
__global__ __launch_bounds__(256) void attn_k(const unsigned short* __restrict__ qg,
    const unsigned short* __restrict__ kg, const unsigned short* __restrict__ vg,
    unsigned short* __restrict__ ctx) {
  __shared__ unsigned short K_lds[64][136];
  __shared__ unsigned short VT_lds[128][72];
  __shared__ unsigned short P_lds[64][72];
  const int t = threadIdx.x, lane = t & 63, w = t >> 6;
  const int lr = lane & 15, lg = lane >> 4;
  const int qt = blockIdx.x, bh = blockIdx.y;
  const int q0 = qt * 64;
  const size_t base = (size_t)bh * S_ * DH_;
  const int qrow = q0 + w * 16 + lr;

  bf16x8 qf[4];
#pragma unroll
  for (int ks = 0; ks < 4; ++ks) {
    bf16x8 z; 
#pragma unroll
    for (int e = 0; e < 8; ++e) z[e] = 0;
    if (qrow < S_) z = *reinterpret_cast<const bf16x8*>(&qg[base + (size_t)qrow * DH_ + ks * 32 + lg * 8]);
    qf[ks] = z;
  }
  float mst[4], lst[4];
  f32x4 cacc[8];
#pragma unroll
  for (int r = 0; r < 4; ++r) { mst[r] = -1e30f; lst[r] = 0.f; }
#pragma unroll
  for (int f = 0; f < 8; ++f) cacc[f] = zero4();

  for (int kt = 0; kt <= qt; ++kt) {
    const int kv0 = kt * 64;
    __syncthreads();
    // stage K [64][128]
#pragma unroll
    for (int j = 0; j < 4; ++j) {
      int qq = t + 256 * j;
      int row = qq >> 4, c8 = (qq & 15) << 3;
      int4 v; v.x = 0; v.y = 0; v.z = 0; v.w = 0;
      if (kv0 + row < S_) v = *reinterpret_cast<const int4*>(&kg[base + (size_t)(kv0 + row) * DH_ + c8]);
      *reinterpret_cast<int4*>(&K_lds[row][c8]) = v;
    }
    // stage V transposed [128][64]
#pragma unroll
    for (int j = 0; j < 4; ++j) {
      int qq = t + 256 * j;
      int row = qq >> 4, c8 = (qq & 15) << 3;
      int4 v; v.x = 0; v.y = 0; v.z = 0; v.w = 0;
      if (kv0 + row < S_) v = *reinterpret_cast<const int4*>(&vg[base + (size_t)(kv0 + row) * DH_ + c8]);
      unsigned ux;
      ux = (unsigned)v.x; VT_lds[c8 + 0][row] = ux & 0xffff; VT_lds[c8 + 1][row] = ux >> 16;
      ux = (unsigned)v.y; VT_lds[c8 + 2][row] = ux & 0xffff; VT_lds[c8 + 3][row] = ux >> 16;
      ux = (unsigned)v.z; VT_lds[c8 + 4][row] = ux & 0xffff; VT_lds[c8 + 5][row] = ux >> 16;
      ux = (unsigned)v.w; VT_lds[c8 + 6][row] = ux & 0xffff; VT_lds[c8 + 7][row] = ux >> 16;
    }
    __syncthreads();

    // QK^T: 16 q-rows x 64 kv
    f32x4 sacc[4];
#pragma unroll
    for (int c = 0; c < 4; ++c) sacc[c] = zero4();
#pragma unroll
    for (int ks = 0; ks < 4; ++ks) {
#pragma unroll
      for (int c = 0; c < 4; ++c) {
        bf16x8 kf = *reinterpret_cast<const bf16x8*>(&K_lds[c * 16 + lr][ks * 32 + lg * 8]);
        sacc[c] = mfma16(qf[ks], kf, sacc[c]);
      }
    }
    // scale + causal mask
    float sc[4][4], mx[4];
#pragma unroll
    for (int r = 0; r < 4; ++r) mx[r] = -1e30f;
#pragma unroll
    for (int c = 0; c < 4; ++c) {
      int col = kv0 + c * 16 + lr;
#pragma unroll
      for (int r = 0; r < 4; ++r) {
        int rowq = q0 + w * 16 + lg * 4 + r;
        float v = sacc[c][r] * 0.08838834764831845f;  // 1/sqrt(128)
        if (col > rowq || col >= S_) v = -1e30f;
        sc[c][r] = v;
        mx[r] = fmaxf(mx[r], v);
      }
    }
    // row reduce over the 16-lane group
#pragma unroll
    for (int m = 1; m < 16; m <<= 1)
#pragma unroll
      for (int r = 0; r < 4; ++r) mx[r] = fmaxf(mx[r], __shfl_xor(mx[r], m));
    float corr[4], rsm[4];
#pragma unroll
    for (int r = 0; r < 4; ++r) {
      float mn = fmaxf(mst[r], mx[r]);
      corr[r] = __expf(mst[r] - mn);
      mst[r] = mn;
      float s = 0.f;
#pragma unroll
      for (int c = 0; c < 4; ++c) { float p = __expf(sc[c][r] - mn); sc[c][r] = p; s += p; }
      rsm[r] = s;
    }
#pragma unroll
    for (int m = 1; m < 16; m <<= 1)
#pragma unroll
      for (int r = 0; r < 4; ++r) rsm[r] += __shfl_xor(rsm[r], m);
#pragma unroll
    for (int r = 0; r < 4; ++r) lst[r] = lst[r] * corr[r] + rsm[r];
#pragma unroll
    for (int f = 0; f < 8; ++f)
#pragma unroll
      for (int r = 0; r < 4; ++r) cacc[f][r] *= corr[r];
    // P -> LDS (bf16)
#pragma unroll
    for (int c = 0; c < 4; ++c)
#pragma unroll
      for (int r = 0; r < 4; ++r)
        P_lds[w * 16 + lg * 4 + r][c * 16 + lr] = f2bf(sc[c][r]);
    __syncthreads();
    // PV
#pragma unroll
    for (int ks = 0; ks < 2; ++ks) {
      bf16x8 pf = *reinterpret_cast<const bf16x8*>(&P_lds[w * 16 + lr][ks * 32 + lg * 8]);
#pragma unroll
      for (int f = 0; f < 8; ++f) {
        bf16x8 vf = *reinterpret_cast<const bf16x8*>(&VT_lds[f * 16 + lr][ks * 32 + lg * 8]);
        cacc[f] = mfma16(pf, vf, cacc[f]);
      }
    }
  }
  // write ctx [b][s][h*128+d] bf16
  const int b = bh >> 4, hh = bh & 15;
  float inv[4];
#pragma unroll
  for (int r = 0; r < 4; ++r) inv[r] = 1.f / lst[r];
#pragma unroll
  for (int f = 0; f < 8; ++f)
#pragma unroll
    for (int r = 0; r < 4; ++r) {
      int qgl = q0 + w * 16 + lg * 4 + r;
      if (qgl < S_)
        ctx[((size_t)(b * S_ + qgl)) * D_ + hh * DH_ + f * 16 + lr] = f2bf(cacc[f][r] * inv[r]);
    }
}

// ---------------- mean pool over sequence ----------------
__global__ __launch_bounds__(256) void meanpool(const unsigned short* __restrict__ xn,
    float* __restrict__ out) {
  int d = blockIdx.x * 256 + threadIdx.x;
  int b = blockIdx.y;
  const unsigned short* p = xn + (size_t)b * S_ * D_ + d;
  float s = 0.f;
  for (int i = 0; i < S_; ++i) s += bf2f(p[(size_t)i * D_]);
  out[(size_t)b * D_ + d] = s * (1.f / S_);
}

// ---------------- series branch: adds into out ----------------
__global__ __launch_bounds__(256) void series_k(const float* __restrict__ x,
    const float* __restrict__ pw, const float* __restrict__ pb, float* out) {
  __shared__ float sm[T_];
  __shared__ float emb[D_];
  __shared__ float red[4];
  int b = blockIdx.x, t = threadIdx.x;
  if (t < T_) {
    float s = 0.f;
    for (int c = 0; c < C_; ++c) s += x[((size_t)b * C_ + c) * T_ + t];
    sm[t] = s * (1.f / C_);
  }
  __syncthreads();
  float ssq = 0.f;
#pragma unroll
  for (int j = 0; j < D_ / 256; ++j) {
    int d = j * 256 + t;
    float e = pb[d];
    for (int tt = 0; tt < T_; ++tt) e += sm[tt] * pw[(size_t)d * T_ + tt];
    emb[d] = e;
    ssq += e * e;
  }
#pragma unroll
  for (int m = 1; m < 64; m <<= 1) ssq += __shfl_xor(ssq, m);
  if ((t & 63) == 0) red[t >> 6] = ssq;
  __syncthreads();
  float tot = red[0] + red[1] + red[2] + red[3];
  float inv = 1.f / fmaxf(sqrtf(tot), 1e-12f);
#pragma unroll
  for (int j = 0; j < D_ / 256; ++j) {
    int d = j * 256 + t;
    out[(size_t)b * D_ + d] += emb[d] * inv;
  }
}

extern "C" void kernel_launch(void* const* d_in, const int* in_sizes, int n_in,
                              void* d_out, int out_size, void* d_ws, size_t ws_size,
                              hipStream_t stream) {
  const float* x      = (const float*)d_in[0];
  const int*   tok    = (const int*)d_in[1];
  const float* embedw = (const float*)d_in[2];
  const int*   wq_idx = (const int*)d_in[3];
  const float* wq_sc  = (const float*)d_in[4];
  const int*   wk_idx = (const int*)d_in[5];
  const float* wk_sc  = (const float*)d_in[6];
  const int*   wv_idx = (const int*)d_in[7];
  const float* wv_sc  = (const float*)d_in[8];
  const int*   wo_idx = (const int*)d_in[9];
  const float* wo_sc  = (const float*)d_in[10];
  const int*   wg_idx = (const int*)d_in[11];
  const float* wg_sc  = (const float*)d_in[12];
  const int*   wu_idx = (const int*)d_in[13];
  const float* wu_sc  = (const float*)d_in[14];
  const int*   wd_idx = (const int*)d_in[15];
  const float* wd_sc  = (const float*)d_in[16];
  const float* ln1    = (const float*)d_in[17];
  const float* ln2    = (const float*)d_in[18];
  const float* lnf    = (const float*)d_in[19];
  const float* projw  = (const float*)d_in[20];
  const float* projb  = (const float*)d_in[21];
  float* out = (float*)d_out;
  (void)in_sizes; (void)n_in; (void)out_size; (void)ws_size;

  char* wsp = (char*)d_ws;
  size_t off = 0;
  auto alloc = [&](size_t bytes) -> void* {
    void* p = wsp + off; off += (bytes + 255) & ~(size_t)255; return p; };
  float* cosT = (float*)alloc((size_t)S_ * DH_ * 4);
  float* sinT = (float*)alloc((size_t)S_ * DH_ * 4);
  float* hbuf = (float*)alloc((size_t)M_ * D_ * 4);
  unsigned short* xn  = (unsigned short*)alloc((size_t)M_ * D_ * 2);
  unsigned short* qb  = (unsigned short*)alloc((size_t)B_ * H_ * S_ * DH_ * 2);
  unsigned short* kb  = (unsigned short*)alloc((size_t)B_ * H_ * S_ * DH_ * 2);
  unsigned short* vb  = (unsigned short*)alloc((size_t)B_ * H_ * S_ * DH_ * 2);
  unsigned short* wdeq = (unsigned short*)alloc((size_t)DFF_ * D_ * 2);  // 22.5 MB
  unsigned short* ctx = xn;     // alias: xn dead during attention, rewritten after O-GEMM
  unsigned short* gbuf = qb;    // alias: 44MB g/act spans q+k+v (49MB), dead during MLP

  rope_tables<<<S_, DH_, 0, stream>>>(cosT, sinT);
  embed_gather<<<M_, 256, 0, stream>>>(tok, embedw, hbuf);

  const int nxAtt = D_ / 128;                 // 16
  const int nxMlp = DFF_ / 128;               // 43
  const int my = (M_ + 127) / 128;            // 32
  const dim3 gAtt(nxAtt * my);                // 512 blocks
  const dim3 gMlp(nxMlp * my);                // 1376 blocks
  const dim3 dqD(1, D_), dqF(1, DFF_), dqK(3, D_);  // dequant grids (K=2048 / K=2048 / K=5504)

  for (int l = 0; l < L_N; ++l) {
    const int*   wqi = wq_idx + (size_t)l * D_ * D_;
    const float* wqs = wq_sc + (size_t)l * D_ * (D_ / 64);
    const int*   wki = wk_idx + (size_t)l * D_ * D_;
    const float* wks = wk_sc + (size_t)l * D_ * (D_ / 64);
    const int*   wvi = wv_idx + (size_t)l * D_ * D_;
    const float* wvs = wv_sc + (size_t)l * D_ * (D_ / 64);
    const int*   woi = wo_idx + (size_t)l * D_ * D_;
    const float* wos = wo_sc + (size_t)l * D_ * (D_ / 64);
    const int*   wgi = wg_idx + (size_t)l * DFF_ * D_;
    const float* wgs = wg_sc + (size_t)l * DFF_ * (D_ / 64);
    const int*   wui = wu_idx + (size_t)l * DFF_ * D_;
    const float* wus = wu_sc + (size_t)l * DFF_ * (D_ / 64);
    const int*   wdi = wd_idx + (size_t)l * D_ * DFF_;
    const float* wds = wd_sc + (size_t)l * D_ * (DFF_ / 64);

    rmsnorm_k<<<M_, 256, 0, stream>>>(hbuf, ln1 + l * D_, xn);
    dequant_k<<<dqD, 256, 0, stream>>>(wqi, wqs, wdeq, D_);
    gemm_bf16<1><<<gAtt, 256, 0, stream>>>(xn, wdeq, M_, D_, D_, nxAtt, qb, nullptr);
    dequant_k<<<dqD, 256, 0, stream>>>(wki, wks, wdeq, D_);
    gemm_bf16<1><<<gAtt, 256, 0, stream>>>(xn, wdeq, M_, D_, D_, nxAtt, kb, nullptr);
    dequant_k<<<dqD, 256, 0, stream>>>(wvi, wvs, wdeq, D_);
    gemm_bf16<1><<<gAtt, 256, 0, stream>>>(xn, wdeq, M_, D_, D_, nxAtt, vb, nullptr);
    rope_apply<<<(B_ * H_ * S_ * 64) / 256, 256, 0, stream>>>(qb, kb, cosT, sinT);
    attn_k<<<dim3(16, B_ * H_), 256, 0, stream>>>(qb, kb, vb, ctx);
    dequant_k<<<dqD, 256, 0, stream>>>(woi, wos, wdeq, D_);
    gemm_bf16<3><<<gAtt, 256, 0, stream>>>(ctx, wdeq, M_, D_, D_, nxAtt, hbuf, nullptr);
    rmsnorm_k<<<M_, 256, 0, stream>>>(hbuf, ln2 + l * D_, xn);
    dequant_k<<<dqF, 256, 0, stream>>>(wgi, wgs, wdeq, D_);
    gemm_bf16<0><<<gMlp, 256, 0, stream>>>(xn, wdeq, M_, DFF_, D_, nxMlp, gbuf, nullptr);
    dequant_k<<<dqF, 256, 0, stream>>>(wui, wus, wdeq, D_);
    gemm_bf16<2><<<gMlp, 256, 0, stream>>>(xn, wdeq, M_, DFF_, D_, nxMlp, gbuf, gbuf);
    dequant_k<<<dqK, 256, 0, stream>>>(wdi, wds, wdeq, DFF_);
    gemm_bf16<3><<<gAtt, 256, 0, stream>>>(gbuf, wdeq, M_, D_, DFF_, nxAtt, hbuf, nullptr);
  }

  rmsnorm_k<<<M_, 256, 0, stream>>>(hbuf, lnf, xn);
  meanpool<<<dim3(D_ / 256, B_), 256, 0, stream>>>(xn, out);
  series_k<<<B_, 256, 0, stream>>>(x, projw, projb, out);
}

// Round 3
// 1771.192 us; speedup vs baseline: 1.8343x; 1.1632x over previous
//
#include <hip/hip_runtime.h>
#include <hip/hip_bf16.h>

#define L_N 2
#define D_ 2048
#define H_ 16
#define DH_ 128
#define DFF_ 5504
#define B_ 4
#define S_ 1000
#define C_ 7
#define T_ 45
#define M_ 4000   // B_*S_

typedef short bf16x8 __attribute__((ext_vector_type(8)));
typedef float f32x4 __attribute__((ext_vector_type(4)));

__constant__ float NF4_TAB[16] = {
  -1.0f, -0.6961928009986877f, -0.5250730514526367f, -0.39491748809814453f,
  -0.28444138169288635f, -0.18477343022823334f, -0.09105003625154495f, 0.0f,
  0.07958029955625534f, 0.16093020141124725f, 0.24611230194568634f,
  0.3379152417182922f, 0.44070982933044434f, 0.5626170039176941f,
  0.7229568362236023f, 1.0f };

__device__ __forceinline__ unsigned short f2bf(float f) {
  unsigned int u = __float_as_uint(f);
  u += 0x7fffu + ((u >> 16) & 1u);          // RNE
  return (unsigned short)(u >> 16);
}
__device__ __forceinline__ float bf2f(unsigned short u) {
  return __uint_as_float(((unsigned int)u) << 16);
}
__device__ __forceinline__ f32x4 zero4() { f32x4 z; z[0]=0.f; z[1]=0.f; z[2]=0.f; z[3]=0.f; return z; }
__device__ __forceinline__ f32x4 mfma16(bf16x8 a, bf16x8 b, f32x4 c) {
  return __builtin_amdgcn_mfma_f32_16x16x32_bf16(a, b, c, 0, 0, 0);
}

typedef __attribute__((address_space(3))) unsigned int lds_u32;
typedef const __attribute__((address_space(1))) unsigned int glb_u32;
__device__ __forceinline__ void gload16(const void* g, void* l) {
  __builtin_amdgcn_global_load_lds((glb_u32*)g, (lds_u32*)l, 16, 0, 0);
}

// ---------------- rope tables ----------------
__global__ void rope_tables(float* __restrict__ cosT, float* __restrict__ sinT) {
  int s = blockIdx.x, d = threadIdx.x;   // 128 threads
  int j = d & 63;
  float inv = expf(-(float)j * (9.210340371976184f / 64.f)); // 10000^(-j/64)
  float ang = (float)s * inv;
  cosT[s * DH_ + d] = cosf(ang);
  sinT[s * DH_ + d] = sinf(ang);
}

// ---------------- embedding gather ----------------
__global__ __launch_bounds__(256) void embed_gather(const int* __restrict__ tok,
    const float* __restrict__ emb, float* __restrict__ h) {
  int row = blockIdx.x;                 // 0..3999  (b*S+s)
  int tk = tok[row];
  const float4* src = reinterpret_cast<const float4*>(emb + (size_t)tk * D_);
  float4* dst = reinterpret_cast<float4*>(h + (size_t)row * D_);
  dst[threadIdx.x] = src[threadIdx.x];
  dst[threadIdx.x + 256] = src[threadIdx.x + 256];
}

// ---------------- rmsnorm: fp32 in -> bf16 out ----------------
__global__ __launch_bounds__(256) void rmsnorm_k(const float* __restrict__ h,
    const float* __restrict__ w, unsigned short* __restrict__ out) {
  const int row = blockIdx.x, t = threadIdx.x;
  const float* hp = h + (size_t)row * D_;
  float4 a = *reinterpret_cast<const float4*>(&hp[t * 8]);
  float4 b = *reinterpret_cast<const float4*>(&hp[t * 8 + 4]);
  float ss = a.x*a.x + a.y*a.y + a.z*a.z + a.w*a.w
           + b.x*b.x + b.y*b.y + b.z*b.z + b.w*b.w;
#pragma unroll
  for (int m = 1; m < 64; m <<= 1) ss += __shfl_xor(ss, m);
  __shared__ float red[4];
  if ((t & 63) == 0) red[t >> 6] = ss;
  __syncthreads();
  float tot = red[0] + red[1] + red[2] + red[3];
  float rs = rsqrtf(tot * (1.0f / D_) + 1e-5f);
  float4 wa = *reinterpret_cast<const float4*>(&w[t * 8]);
  float4 wb = *reinterpret_cast<const float4*>(&w[t * 8 + 4]);
  unsigned r0 = (unsigned)f2bf(a.x*rs*wa.x) | ((unsigned)f2bf(a.y*rs*wa.y) << 16);
  unsigned r1 = (unsigned)f2bf(a.z*rs*wa.z) | ((unsigned)f2bf(a.w*rs*wa.w) << 16);
  unsigned r2 = (unsigned)f2bf(b.x*rs*wb.x) | ((unsigned)f2bf(b.y*rs*wb.y) << 16);
  unsigned r3 = (unsigned)f2bf(b.z*rs*wb.z) | ((unsigned)f2bf(b.w*rs*wb.w) << 16);
  int4 ov; ov.x = (int)r0; ov.y = (int)r1; ov.z = (int)r2; ov.w = (int)r3;
  *reinterpret_cast<int4*>(&out[(size_t)row * D_ + t * 8]) = ov;
}

// ---------------- NF4 dequant: idx int32 [N][K] + scale -> bf16 [N][K] ----------------
__global__ __launch_bounds__(256) void dequant_k(const int* __restrict__ idx,
    const float* __restrict__ sc, unsigned short* __restrict__ out, int K) {
  __shared__ float nf4[16];
  const int t = threadIdx.x;
  if (t < 16) nf4[t] = NF4_TAB[t];
  __syncthreads();
  const int row = blockIdx.y;
  const int k0 = blockIdx.x * 2048 + t * 8;
  if (k0 >= K) return;
  const size_t base = (size_t)row * K + k0;
  int4 a = *reinterpret_cast<const int4*>(&idx[base]);
  int4 b = *reinterpret_cast<const int4*>(&idx[base + 4]);
  float s = sc[(size_t)row * (K >> 6) + (k0 >> 6)];
  unsigned r0 = (unsigned)f2bf(nf4[a.x & 15] * s) | ((unsigned)f2bf(nf4[a.y & 15] * s) << 16);
  unsigned r1 = (unsigned)f2bf(nf4[a.z & 15] * s) | ((unsigned)f2bf(nf4[a.w & 15] * s) << 16);
  unsigned r2 = (unsigned)f2bf(nf4[b.x & 15] * s) | ((unsigned)f2bf(nf4[b.y & 15] * s) << 16);
  unsigned r3 = (unsigned)f2bf(nf4[b.z & 15] * s) | ((unsigned)f2bf(nf4[b.w & 15] * s) << 16);
  int4 ov; ov.x = (int)r0; ov.y = (int)r1; ov.z = (int)r2; ov.w = (int)r3;
  *reinterpret_cast<int4*>(&out[base]) = ov;
}

// ---------------- bf16 GEMM (m97 structure): C[M][N] = A[M][K] @ W[N][K]^T ----------------
// MODE 0: out bf16 [M][N]
// MODE 1: out bf16 q/k/v layout [B][H][S][DH]
// MODE 2: out bf16 [M][N] = silu(gin) * acc
// MODE 3: out fp32 [M][N] += acc   (residual)
template<int MODE>
__global__ __launch_bounds__(256) void gemm_bf16(
    const unsigned short* __restrict__ A,
    const unsigned short* __restrict__ Bw,
    int Mdim, int N, int K, int nx,
    void* outp, const unsigned short* gin) {
  __shared__ unsigned short A_lds[128 * 64];
  __shared__ unsigned short B_lds[128 * 64];
  const int t = threadIdx.x;
  const int lane = t & 63, wid = t >> 6;

  // bijective XCD swizzle (gridDim.x % 8 == 0 for all our launches)
  const int nwg = gridDim.x;
  const int bid = blockIdx.x;
  const int wg = (bid & 7) * (nwg >> 3) + (bid >> 3);
  const int n0 = (wg % nx) * 128;
  const int m0 = (wg / nx) * 128;

  const int wm = (wid >> 1) * 64, wn = (wid & 1) * 64;
  const int lr = lane & 15, lg = lane >> 4;
  // staging decomposition: chunk = 1024B = 8 rows x 128B; lane covers 16B
  const int lrow = lane >> 3;
  const int lcolb = (lane & 7) << 4;   // byte offset within row

  f32x4 acc[4][4];
#pragma unroll
  for (int i = 0; i < 4; ++i)
#pragma unroll
    for (int j = 0; j < 4; ++j) acc[i][j] = zero4();

  const int kT = K >> 6;
  for (int kt = 0; kt < kT; ++kt) {
    // stage A and B tiles via async global->LDS, 16B per lane
#pragma unroll
    for (int c0 = 0; c0 < 4; ++c0) {
      const int c = wid + 4 * c0;
      int gr = m0 + c * 8 + lrow;
      gr = gr < Mdim ? gr : Mdim - 1;          // clamp: OOB rows discarded in epilogue
      gload16((const char*)A + ((size_t)gr * K + kt * 64) * 2 + lcolb,
              (char*)A_lds + c * 1024);
      const int nr = n0 + c * 8 + lrow;        // always in-bounds (N % 128 == 0)
      gload16((const char*)Bw + ((size_t)nr * K + kt * 64) * 2 + lcolb,
              (char*)B_lds + c * 1024);
    }
    __syncthreads();
#pragma unroll
    for (int ks = 0; ks < 2; ++ks) {
      bf16x8 af[4], bfr[4];
#pragma unroll
      for (int i = 0; i < 4; ++i) {
        af[i]  = *reinterpret_cast<const bf16x8*>(&A_lds[(wm + i * 16 + lr) * 64 + ks * 32 + lg * 8]);
        bfr[i] = *reinterpret_cast<const bf16x8*>(&B_lds[(wn + i * 16 + lr) * 64 + ks * 32 + lg * 8]);
      }
#pragma unroll
      for (int mi = 0; mi < 4; ++mi)
#pragma unroll
        for (int ni = 0; ni < 4; ++ni)
          acc[mi][ni] = mfma16(af[mi], bfr[ni], acc[mi][ni]);
    }
    __syncthreads();
  }

  // epilogue: C row = m0+wm+mi*16+lg*4+r, col = n0+wn+ni*16+lr
#pragma unroll
  for (int mi = 0; mi < 4; ++mi) {
#pragma unroll
    for (int r = 0; r < 4; ++r) {
      int gm = m0 + wm + mi * 16 + lg * 4 + r;
      if (gm >= Mdim) continue;
#pragma unroll
      for (int ni = 0; ni < 4; ++ni) {
        int gn = n0 + wn + ni * 16 + lr;
        float v = acc[mi][ni][r];
        if (MODE == 0) {
          ((unsigned short*)outp)[(size_t)gm * N + gn] = f2bf(v);
        } else if (MODE == 1) {
          int b = gm / S_, s = gm - b * S_;
          int hh = gn >> 7, d = gn & 127;
          ((unsigned short*)outp)[(((size_t)(b * H_ + hh) * S_ + s) << 7) + d] = f2bf(v);
        } else if (MODE == 2) {
          float g = bf2f(gin[(size_t)gm * N + gn]);
          float sg = g / (1.f + __expf(-g));
          ((unsigned short*)outp)[(size_t)gm * N + gn] = f2bf(sg * v);
        } else {
          ((float*)outp)[(size_t)gm * N + gn] += v;
        }
      }
    }
  }
}

// ---------------- rope apply (in-place, q & k) ----------------
__global__ __launch_bounds__(256) void rope_apply(unsigned short* __restrict__ qb,
    unsigned short* __restrict__ kb, const float* __restrict__ cosT,
    const float* __restrict__ sinT) {
  size_t i = (size_t)blockIdx.x * 256 + threadIdx.x;  // B*H*S*64 slots
  int d = (int)(i & 63);
  size_t row = i >> 6;              // (b*H+h)*S + s
  int s = (int)(row % S_);
  size_t base = row * DH_;
  float c = cosT[s * DH_ + d], sn = sinT[s * DH_ + d];
  float q0 = bf2f(qb[base + d]), q1 = bf2f(qb[base + d + 64]);
  qb[base + d]      = f2bf(q0 * c - q1 * sn);
  qb[base + d + 64] = f2bf(q1 * c + q0 * sn);
  float k0 = bf2f(kb[base + d]), k1 = bf2f(kb[base + d + 64]);
  kb[base + d]      = f2bf(k0 * c - k1 * sn);
  kb[base + d + 64] = f2bf(k1 * c + k0 * sn);
}

// ---------------- V transpose: vb [b][h][s][128] -> vt [bh][128][1024] ----------------
__global__ __launch_bounds__(256) void vtrans_k(const unsigned short* __restrict__ vb,
    unsigned short* __restrict__ vt) {
  __shared__ unsigned int tile[64][33];
  const int t = threadIdx.x;
  const int s0 = blockIdx.x * 64, d0 = blockIdx.y * 64, bh = blockIdx.z;
#pragma unroll
  for (int j = 0; j < 2; ++j) {
    int idx = t + 256 * j;
    int s_r = idx >> 3, c8 = (idx & 7) << 3;
    int srow = s0 + s_r; srow = srow < S_ ? srow : S_ - 1;
    int4 v = *reinterpret_cast<const int4*>(&vb[((size_t)bh * S_ + srow) * DH_ + d0 + c8]);
    tile[s_r][(c8 >> 1) + 0] = (unsigned)v.x;
    tile[s_r][(c8 >> 1) + 1] = (unsigned)v.y;
    tile[s_r][(c8 >> 1) + 2] = (unsigned)v.z;
    tile[s_r][(c8 >> 1) + 3] = (unsigned)v.w;
  }
  __syncthreads();
#pragma unroll
  for (int j = 0; j < 2; ++j) {
    int idx = t + 256 * j;
    int d_r = idx >> 3, s8 = (idx & 7) << 3;
    unsigned r[8];
#pragma unroll
    for (int e = 0; e < 8; ++e) {
      unsigned wv = tile[s8 + e][d_r >> 1];
      r[e] = (d_r & 1) ? (wv >> 16) : (wv & 0xffffu);
    }
    int4 ov;
    ov.x = (int)(r[0] | (r[1] << 16));
    ov.y = (int)(r[2] | (r[3] << 16));
    ov.z = (int)(r[4] | (r[5] << 16));
    ov.w = (int)(r[6] | (r[7] << 16));
    *reinterpret_cast<int4*>(&vt[((size_t)(bh * 128 + d0 + d_r)) * 1024 + s0 + s8]) = ov;
  }
}

// ---------------- causal flash attention v2 (swapped-QK, 8 waves, 128 q rows) --------
// grid (B*H, 8); S^T = mfma(K,Q) so q = lane&15 -> per-lane scalar m/l;
// PV: O^T = mfma(V^T, P^T), P^T built in-register via packed shfl.
__global__ __launch_bounds__(512, 4) void attn2_k(const unsigned short* __restrict__ qg,
    const unsigned short* __restrict__ kg, const unsigned short* __restrict__ vtg,
    unsigned short* __restrict__ ctx) {
  __shared__ unsigned short K_lds[64 * 128];
  __shared__ unsigned short VT_lds[128 * 64];
  const int t = threadIdx.x, lane = t & 63, w = t >> 6;
  const int lr = lane & 15, lg = lane >> 4;
  const int bh = blockIdx.x, qt = blockIdx.y;
  const int q0 = qt * 128;
  const int b = bh >> 4, hh = bh & 15;
  const size_t kbase2 = (size_t)bh * S_ * DH_ * 2;   // byte base of this head
  const int q_idx = q0 + w * 16 + lr;
  const int swz = (lr & 7) << 4;

  bf16x8 qf[4];
#pragma unroll
  for (int ks = 0; ks < 4; ++ks) {
    bf16x8 z;
#pragma unroll
    for (int e = 0; e < 8; ++e) z[e] = 0;
    if (q_idx < S_)
      z = *reinterpret_cast<const bf16x8*>(
            (const char*)qg + kbase2 + (size_t)q_idx * 256 + ks * 64 + lg * 16);
    qf[ks] = z;
  }
  float mst = -1e30f, lst = 0.f;
  f32x4 cacc[8];
#pragma unroll
  for (int f = 0; f < 8; ++f) cacc[f] = zero4();

  const int q_hi = (q0 + 127 < S_) ? q0 + 127 : S_ - 1;
  const int nt = q_hi / 64 + 1;
  const int wq_max = q0 + w * 16 + 15;

  for (int kt = 0; kt < nt; ++kt) {
    const int kv0 = kt * 64;
    __syncthreads();
    // stage K [64][128] and VT [128][64], XOR-swizzled source -> linear LDS
#pragma unroll
    for (int j = 0; j < 2; ++j) {
      const int chunk = w + 8 * j;            // 0..15, 1024B each
      int krow = chunk * 4 + (lane >> 4);     // 4 rows x 256B
      int kcolb = (lane & 15) << 4;
      int gr = kv0 + krow; gr = gr < S_ ? gr : S_ - 1;
      gload16((const char*)kg + kbase2 + (size_t)gr * 256 + (kcolb ^ ((krow & 7) << 4)),
              (char*)K_lds + chunk * 1024);
      int vrow = chunk * 8 + (lane >> 3);     // 8 rows x 128B
      int vcolb = (lane & 7) << 4;
      gload16((const char*)vtg + ((size_t)(bh * 128 + vrow) * 1024 + kv0) * 2 + (vcolb ^ ((vrow & 7) << 4)),
              (char*)VT_lds + chunk * 1024);
    }
    __syncthreads();
    if (kv0 > wq_max) continue;               // whole wave masked this tile

    // S^T = K . Q^T  (row = kv, col = q = lr)
    f32x4 sacc[4];
#pragma unroll
    for (int c = 0; c < 4; ++c) sacc[c] = zero4();
#pragma unroll
    for (int ks = 0; ks < 4; ++ks) {
#pragma unroll
      for (int c = 0; c < 4; ++c) {
        bf16x8 kf = *reinterpret_cast<const bf16x8*>(
            &K_lds[(c * 16 + lr) * 128 + (((ks * 64 + lg * 16) ^ swz) >> 1)]);
        sacc[c] = mfma16(kf, qf[ks], sacc[c]);
      }
    }
    // mask + online softmax (per-lane scalar m/l; reduce across lg groups)
    float p[4][4];
    float mx = -1e30f;
#pragma unroll
    for (int c = 0; c < 4; ++c)
#pragma unroll
      for (int r = 0; r < 4; ++r) {
        int kv = kv0 + c * 16 + lg * 4 + r;
        float v = sacc[c][r] * 0.08838834764831845f;   // 1/sqrt(128)
        if (kv > q_idx || kv >= S_) v = -1e30f;
        p[c][r] = v;
        mx = fmaxf(mx, v);
      }
    mx = fmaxf(mx, __shfl_xor(mx, 16));
    mx = fmaxf(mx, __shfl_xor(mx, 32));
    float mn = fmaxf(mst, mx);
    float corr = __expf(mst - mn);
    mst = mn;
    float rs = 0.f;
#pragma unroll
    for (int c = 0; c < 4; ++c)
#pragma unroll
      for (int r = 0; r < 4; ++r) {
        float e = __expf(p[c][r] - mn);
        p[c][r] = e;
        rs += e;
      }
    rs += __shfl_xor(rs, 16);
    rs += __shfl_xor(rs, 32);
    lst = lst * corr + rs;
#pragma unroll
    for (int f = 0; f < 8; ++f)
#pragma unroll
      for (int r = 0; r < 4; ++r) cacc[f][r] *= corr;

    // pack P (bf16 pairs) and redistribute to PV B-operand via shfl
    unsigned pk01[4], pk23[4];
#pragma unroll
    for (int c = 0; c < 4; ++c) {
      pk01[c] = (unsigned)f2bf(p[c][0]) | ((unsigned)f2bf(p[c][1]) << 16);
      pk23[c] = (unsigned)f2bf(p[c][2]) | ((unsigned)f2bf(p[c][3]) << 16);
    }
#pragma unroll
    for (int ks = 0; ks < 2; ++ks) {
      unsigned bu[4];
#pragma unroll
      for (int jj = 0; jj < 4; ++jj) {
        const int srcl = ((lg & 1) * 2 + (jj >> 1)) * 16 + lr;
        unsigned lo = (unsigned)__shfl((int)((jj & 1) ? pk23[2 * ks]     : pk01[2 * ks]),     srcl);
        unsigned hi = (unsigned)__shfl((int)((jj & 1) ? pk23[2 * ks + 1] : pk01[2 * ks + 1]), srcl);
        bu[jj] = (lg >= 2) ? hi : lo;
      }
      union { unsigned u[4]; bf16x8 v; } pb;
      pb.u[0] = bu[0]; pb.u[1] = bu[1]; pb.u[2] = bu[2]; pb.u[3] = bu[3];
#pragma unroll
      for (int f = 0; f < 8; ++f) {
        bf16x8 vtf = *reinterpret_cast<const bf16x8*>(
            &VT_lds[(f * 16 + lr) * 64 + (((ks * 64 + lg * 16) ^ swz) >> 1)]);
        cacc[f] = mfma16(vtf, pb.v, cacc[f]);
      }
    }
  }

  // O^T frag: col = q = lr, row = d = f*16 + lg*4 + r  -> packed 8B stores
  if (q_idx < S_) {
    float inv = 1.f / lst;
    unsigned short* cp = ctx + ((size_t)(b * S_ + q_idx)) * D_ + hh * 128;
#pragma unroll
    for (int f = 0; f < 8; ++f) {
      unsigned lo = (unsigned)f2bf(cacc[f][0] * inv) | ((unsigned)f2bf(cacc[f][1] * inv) << 16);
      unsigned hi = (unsigned)f2bf(cacc[f][2] * inv) | ((unsigned)f2bf(cacc[f][3] * inv) << 16);
      uint2 ov; ov.x = lo; ov.y = hi;
      *reinterpret_cast<uint2*>(cp + f * 16 + lg * 4) = ov;
    }
  }
}

// ---------------- mean pool over sequence ----------------
__global__ __launch_bounds__(256) void meanpool(const unsigned short* __restrict__ xn,
    float* __restrict__ out) {
  int d = blockIdx.x * 256 + threadIdx.x;
  int b = blockIdx.y;
  const unsigned short* p = xn + (size_t)b * S_ * D_ + d;
  float s = 0.f;
  for (int i = 0; i < S_; ++i) s += bf2f(p[(size_t)i * D_]);
  out[(size_t)b * D_ + d] = s * (1.f / S_);
}

// ---------------- series branch: adds into out ----------------
__global__ __launch_bounds__(256) void series_k(const float* __restrict__ x,
    const float* __restrict__ pw, const float* __restrict__ pb, float* out) {
  __shared__ float sm[T_];
  __shared__ float emb[D_];
  __shared__ float red[4];
  int b = blockIdx.x, t = threadIdx.x;
  if (t < T_) {
    float s = 0.f;
    for (int c = 0; c < C_; ++c) s += x[((size_t)b * C_ + c) * T_ + t];
    sm[t] = s * (1.f / C_);
  }
  __syncthreads();
  float ssq = 0.f;
#pragma unroll
  for (int j = 0; j < D_ / 256; ++j) {
    int d = j * 256 + t;
    float e = pb[d];
    for (int tt = 0; tt < T_; ++tt) e += sm[tt] * pw[(size_t)d * T_ + tt];
    emb[d] = e;
    ssq += e * e;
  }
#pragma unroll
  for (int m = 1; m < 64; m <<= 1) ssq += __shfl_xor(ssq, m);
  if ((t & 63) == 0) red[t >> 6] = ssq;
  __syncthreads();
  float tot = red[0] + red[1] + red[2] + red[3];
  float inv = 1.f / fmaxf(sqrtf(tot), 1e-12f);
#pragma unroll
  for (int j = 0; j < D_ / 256; ++j) {
    int d = j * 256 + t;
    out[(size_t)b * D_ + d] += emb[d] * inv;
  }
}

extern "C" void kernel_launch(void* const* d_in, const int* in_sizes, int n_in,
                              void* d_out, int out_size, void* d_ws, size_t ws_size,
                              hipStream_t stream) {
  const float* x      = (const float*)d_in[0];
  const int*   tok    = (const int*)d_in[1];
  const float* embedw = (const float*)d_in[2];
  const int*   wq_idx = (const int*)d_in[3];
  const float* wq_sc  = (const float*)d_in[4];
  const int*   wk_idx = (const int*)d_in[5];
  const float* wk_sc  = (const float*)d_in[6];
  const int*   wv_idx = (const int*)d_in[7];
  const float* wv_sc  = (const float*)d_in[8];
  const int*   wo_idx = (const int*)d_in[9];
  const float* wo_sc  = (const float*)d_in[10];
  const int*   wg_idx = (const int*)d_in[11];
  const float* wg_sc  = (const float*)d_in[12];
  const int*   wu_idx = (const int*)d_in[13];
  const float* wu_sc  = (const float*)d_in[14];
  const int*   wd_idx = (const int*)d_in[15];
  const float* wd_sc  = (const float*)d_in[16];
  const float* ln1    = (const float*)d_in[17];
  const float* ln2    = (const float*)d_in[18];
  const float* lnf    = (const float*)d_in[19];
  const float* projw  = (const float*)d_in[20];
  const float* projb  = (const float*)d_in[21];
  float* out = (float*)d_out;
  (void)in_sizes; (void)n_in; (void)out_size; (void)ws_size;

  char* wsp = (char*)d_ws;
  size_t off = 0;
  auto alloc = [&](size_t bytes) -> void* {
    void* p = wsp + off; off += (bytes + 255) & ~(size_t)255; return p; };
  float* cosT = (float*)alloc((size_t)S_ * DH_ * 4);
  float* sinT = (float*)alloc((size_t)S_ * DH_ * 4);
  float* hbuf = (float*)alloc((size_t)M_ * D_ * 4);
  unsigned short* xn  = (unsigned short*)alloc((size_t)M_ * D_ * 2);
  unsigned short* qb  = (unsigned short*)alloc((size_t)B_ * H_ * S_ * DH_ * 2);
  unsigned short* kb  = (unsigned short*)alloc((size_t)B_ * H_ * S_ * DH_ * 2);
  unsigned short* vb  = (unsigned short*)alloc((size_t)B_ * H_ * S_ * DH_ * 2);
  unsigned short* wdeq = (unsigned short*)alloc((size_t)DFF_ * D_ * 2);  // 22.5 MB
  unsigned short* ctx = xn;     // alias: xn dead during attention, rewritten after O-GEMM
  unsigned short* gbuf = qb;    // alias: 44MB g/act spans q+k+v (49MB), dead during MLP
  unsigned short* vt  = wdeq;   // alias: V^T [bh][128][1024] (16.8MB), dead before O-dequant

  rope_tables<<<S_, DH_, 0, stream>>>(cosT, sinT);
  embed_gather<<<M_, 256, 0, stream>>>(tok, embedw, hbuf);

  const int nxAtt = D_ / 128;                 // 16
  const int nxMlp = DFF_ / 128;               // 43
  const int my = (M_ + 127) / 128;            // 32
  const dim3 gAtt(nxAtt * my);                // 512 blocks
  const dim3 gMlp(nxMlp * my);                // 1376 blocks
  const dim3 dqD(1, D_), dqF(1, DFF_), dqK(3, D_);  // dequant grids

  for (int l = 0; l < L_N; ++l) {
    const int*   wqi = wq_idx + (size_t)l * D_ * D_;
    const float* wqs = wq_sc + (size_t)l * D_ * (D_ / 64);
    const int*   wki = wk_idx + (size_t)l * D_ * D_;
    const float* wks = wk_sc + (size_t)l * D_ * (D_ / 64);
    const int*   wvi = wv_idx + (size_t)l * D_ * D_;
    const float* wvs = wv_sc + (size_t)l * D_ * (D_ / 64);
    const int*   woi = wo_idx + (size_t)l * D_ * D_;
    const float* wos = wo_sc + (size_t)l * D_ * (D_ / 64);
    const int*   wgi = wg_idx + (size_t)l * DFF_ * D_;
    const float* wgs = wg_sc + (size_t)l * DFF_ * (D_ / 64);
    const int*   wui = wu_idx + (size_t)l * DFF_ * D_;
    const float* wus = wu_sc + (size_t)l * DFF_ * (D_ / 64);
    const int*   wdi = wd_idx + (size_t)l * D_ * DFF_;
    const float* wds = wd_sc + (size_t)l * D_ * (DFF_ / 64);

    rmsnorm_k<<<M_, 256, 0, stream>>>(hbuf, ln1 + l * D_, xn);
    dequant_k<<<dqD, 256, 0, stream>>>(wqi, wqs, wdeq, D_);
    gemm_bf16<1><<<gAtt, 256, 0, stream>>>(xn, wdeq, M_, D_, D_, nxAtt, qb, nullptr);
    dequant_k<<<dqD, 256, 0, stream>>>(wki, wks, wdeq, D_);
    gemm_bf16<1><<<gAtt, 256, 0, stream>>>(xn, wdeq, M_, D_, D_, nxAtt, kb, nullptr);
    dequant_k<<<dqD, 256, 0, stream>>>(wvi, wvs, wdeq, D_);
    gemm_bf16<1><<<gAtt, 256, 0, stream>>>(xn, wdeq, M_, D_, D_, nxAtt, vb, nullptr);
    rope_apply<<<(B_ * H_ * S_ * 64) / 256, 256, 0, stream>>>(qb, kb, cosT, sinT);
    vtrans_k<<<dim3(16, 2, B_ * H_), 256, 0, stream>>>(vb, vt);
    attn2_k<<<dim3(B_ * H_, 8), 512, 0, stream>>>(qb, kb, vt, ctx);
    dequant_k<<<dqD, 256, 0, stream>>>(woi, wos, wdeq, D_);
    gemm_bf16<3><<<gAtt, 256, 0, stream>>>(ctx, wdeq, M_, D_, D_, nxAtt, hbuf, nullptr);
    rmsnorm_k<<<M_, 256, 0, stream>>>(hbuf, ln2 + l * D_, xn);
    dequant_k<<<dqF, 256, 0, stream>>>(wgi, wgs, wdeq, D_);
    gemm_bf16<0><<<gMlp, 256, 0, stream>>>(xn, wdeq, M_, DFF_, D_, nxMlp, gbuf, nullptr);
    dequant_k<<<dqF, 256, 0, stream>>>(wui, wus, wdeq, D_);
    gemm_bf16<2><<<gMlp, 256, 0, stream>>>(xn, wdeq, M_, DFF_, D_, nxMlp, gbuf, gbuf);
    dequant_k<<<dqK, 256, 0, stream>>>(wdi, wds, wdeq, DFF_);
    gemm_bf16<3><<<gAtt, 256, 0, stream>>>(gbuf, wdeq, M_, D_, DFF_, nxAtt, hbuf, nullptr);
  }

  rmsnorm_k<<<M_, 256, 0, stream>>>(hbuf, lnf, xn);
  meanpool<<<dim3(D_ / 256, B_), 256, 0, stream>>>(xn, out);
  series_k<<<B_, 256, 0, stream>>>(x, projw, projb, out);
}

// Round 4
// 1456.843 us; speedup vs baseline: 2.2301x; 1.2158x over previous
//
#include <hip/hip_runtime.h>
#include <hip/hip_bf16.h>

#define L_N 2
#define D_ 2048
#define H_ 16
#define DH_ 128
#define DFF_ 5504
#define B_ 4
#define S_ 1000
#define C_ 7
#define T_ 45
#define M_ 4000   // B_*S_

typedef short bf16x8 __attribute__((ext_vector_type(8)));
typedef float f32x4 __attribute__((ext_vector_type(4)));

__constant__ float NF4_TAB[16] = {
  -1.0f, -0.6961928009986877f, -0.5250730514526367f, -0.39491748809814453f,
  -0.28444138169288635f, -0.18477343022823334f, -0.09105003625154495f, 0.0f,
  0.07958029955625534f, 0.16093020141124725f, 0.24611230194568634f,
  0.3379152417182922f, 0.44070982933044434f, 0.5626170039176941f,
  0.7229568362236023f, 1.0f };

__device__ __forceinline__ unsigned short f2bf(float f) {
  unsigned int u = __float_as_uint(f);
  u += 0x7fffu + ((u >> 16) & 1u);          // RNE
  return (unsigned short)(u >> 16);
}
__device__ __forceinline__ float bf2f(unsigned short u) {
  return __uint_as_float(((unsigned int)u) << 16);
}
__device__ __forceinline__ f32x4 zero4() { f32x4 z; z[0]=0.f; z[1]=0.f; z[2]=0.f; z[3]=0.f; return z; }
__device__ __forceinline__ f32x4 mfma16(bf16x8 a, bf16x8 b, f32x4 c) {
  return __builtin_amdgcn_mfma_f32_16x16x32_bf16(a, b, c, 0, 0, 0);
}

typedef __attribute__((address_space(3))) unsigned int lds_u32;
typedef const __attribute__((address_space(1))) unsigned int glb_u32;
__device__ __forceinline__ void gload16(const void* g, void* l) {
  __builtin_amdgcn_global_load_lds((glb_u32*)g, (lds_u32*)l, 16, 0, 0);
}

// ---------------- rope tables ----------------
__global__ void rope_tables(float* __restrict__ cosT, float* __restrict__ sinT) {
  int s = blockIdx.x, d = threadIdx.x;   // 128 threads
  int j = d & 63;
  float inv = expf(-(float)j * (9.210340371976184f / 64.f)); // 10000^(-j/64)
  float ang = (float)s * inv;
  cosT[s * DH_ + d] = cosf(ang);
  sinT[s * DH_ + d] = sinf(ang);
}

// ---------------- embedding gather ----------------
__global__ __launch_bounds__(256) void embed_gather(const int* __restrict__ tok,
    const float* __restrict__ emb, float* __restrict__ h) {
  int row = blockIdx.x;                 // 0..3999  (b*S+s)
  int tk = tok[row];
  const float4* src = reinterpret_cast<const float4*>(emb + (size_t)tk * D_);
  float4* dst = reinterpret_cast<float4*>(h + (size_t)row * D_);
  dst[threadIdx.x] = src[threadIdx.x];
  dst[threadIdx.x + 256] = src[threadIdx.x + 256];
}

// ---------------- rmsnorm: fp32 in -> bf16 out ----------------
__global__ __launch_bounds__(256) void rmsnorm_k(const float* __restrict__ h,
    const float* __restrict__ w, unsigned short* __restrict__ out) {
  const int row = blockIdx.x, t = threadIdx.x;
  const float* hp = h + (size_t)row * D_;
  float4 a = *reinterpret_cast<const float4*>(&hp[t * 8]);
  float4 b = *reinterpret_cast<const float4*>(&hp[t * 8 + 4]);
  float ss = a.x*a.x + a.y*a.y + a.z*a.z + a.w*a.w
           + b.x*b.x + b.y*b.y + b.z*b.z + b.w*b.w;
#pragma unroll
  for (int m = 1; m < 64; m <<= 1) ss += __shfl_xor(ss, m);
  __shared__ float red[4];
  if ((t & 63) == 0) red[t >> 6] = ss;
  __syncthreads();
  float tot = red[0] + red[1] + red[2] + red[3];
  float rs = rsqrtf(tot * (1.0f / D_) + 1e-5f);
  float4 wa = *reinterpret_cast<const float4*>(&w[t * 8]);
  float4 wb = *reinterpret_cast<const float4*>(&w[t * 8 + 4]);
  unsigned r0 = (unsigned)f2bf(a.x*rs*wa.x) | ((unsigned)f2bf(a.y*rs*wa.y) << 16);
  unsigned r1 = (unsigned)f2bf(a.z*rs*wa.z) | ((unsigned)f2bf(a.w*rs*wa.w) << 16);
  unsigned r2 = (unsigned)f2bf(b.x*rs*wb.x) | ((unsigned)f2bf(b.y*rs*wb.y) << 16);
  unsigned r3 = (unsigned)f2bf(b.z*rs*wb.z) | ((unsigned)f2bf(b.w*rs*wb.w) << 16);
  int4 ov; ov.x = (int)r0; ov.y = (int)r1; ov.z = (int)r2; ov.w = (int)r3;
  *reinterpret_cast<int4*>(&out[(size_t)row * D_ + t * 8]) = ov;
}

// ---------------- NF4 dequant: idx int32 [N][K] + scale -> bf16 [N][K] ----------------
__global__ __launch_bounds__(256) void dequant_k(const int* __restrict__ idx,
    const float* __restrict__ sc, unsigned short* __restrict__ out, int K) {
  __shared__ float nf4[16];
  const int t = threadIdx.x;
  if (t < 16) nf4[t] = NF4_TAB[t];
  __syncthreads();
  const int row = blockIdx.y;
  const int k0 = blockIdx.x * 2048 + t * 8;
  if (k0 >= K) return;
  const size_t base = (size_t)row * K + k0;
  int4 a = *reinterpret_cast<const int4*>(&idx[base]);
  int4 b = *reinterpret_cast<const int4*>(&idx[base + 4]);
  float s = sc[(size_t)row * (K >> 6) + (k0 >> 6)];
  unsigned r0 = (unsigned)f2bf(nf4[a.x & 15] * s) | ((unsigned)f2bf(nf4[a.y & 15] * s) << 16);
  unsigned r1 = (unsigned)f2bf(nf4[a.z & 15] * s) | ((unsigned)f2bf(nf4[a.w & 15] * s) << 16);
  unsigned r2 = (unsigned)f2bf(nf4[b.x & 15] * s) | ((unsigned)f2bf(nf4[b.y & 15] * s) << 16);
  unsigned r3 = (unsigned)f2bf(nf4[b.z & 15] * s) | ((unsigned)f2bf(nf4[b.w & 15] * s) << 16);
  int4 ov; ov.x = (int)r0; ov.y = (int)r1; ov.z = (int)r2; ov.w = (int)r3;
  *reinterpret_cast<int4*>(&out[base]) = ov;
}

// ---------------- bf16 GEMM (dbuf + swizzled LDS): C[M][N] = A[M][K] @ W[N][K]^T -----
// MODE 0: out bf16 [M][N]
// MODE 1: out bf16 q/k/v layout [B][H][S][DH]
// MODE 2: out bf16 [M][N] = silu(gin) * acc
// MODE 3: out fp32 [M][N] += acc   (residual)
template<int MODE>
__global__ __launch_bounds__(256) void gemm_bf16(
    const unsigned short* __restrict__ A,
    const unsigned short* __restrict__ Bw,
    int Mdim, int N, int K, int nx,
    void* outp, const unsigned short* gin) {
  __shared__ unsigned short A_lds[2][128 * 64];   // 2 x 16 KB, XOR-swizzled rows
  __shared__ unsigned short B_lds[2][128 * 64];
  const int t = threadIdx.x;
  const int lane = t & 63, wid = t >> 6;

  // bijective XCD swizzle (gridDim.x % 8 == 0 for all our launches)
  const int nwg = gridDim.x;
  const int bid = blockIdx.x;
  const int wg = (bid & 7) * (nwg >> 3) + (bid >> 3);
  const int n0 = (wg % nx) * 128;
  const int m0 = (wg / nx) * 128;

  const int wm = (wid >> 1) * 64, wn = (wid & 1) * 64;
  const int lr = lane & 15, lg = lane >> 4;
  // staging: chunk = 1024B = 8 rows x 128B; lane's 16B lands linearly at lane*16,
  // so the global source slot is pre-swizzled: logical col = slot ^ (row&7)<<4
  const int lrow = lane >> 3;                       // row within 8-row chunk
  const int lslot = (((lane & 7) ^ lrow) << 4);     // swizzled source byte slot
  const int rswz = (lr & 7) << 4;                   // read-side XOR

  f32x4 acc[4][4];
#pragma unroll
  for (int i = 0; i < 4; ++i)
#pragma unroll
    for (int j = 0; j < 4; ++j) acc[i][j] = zero4();

  const int kT = K >> 6;
  const size_t rowb = (size_t)(K * 2);              // global row stride in bytes

  auto stage = [&](int kt, int b) {
#pragma unroll
    for (int c0 = 0; c0 < 4; ++c0) {
      const int c = wid + 4 * c0;                   // chunk 0..15
      int gr = m0 + c * 8 + lrow;
      gr = gr < Mdim ? gr : Mdim - 1;               // clamp: OOB rows discarded in epilogue
      gload16((const char*)A + (size_t)gr * rowb + kt * 128 + lslot,
              (char*)&A_lds[b][0] + c * 1024);
      const int nr = n0 + c * 8 + lrow;             // always in-bounds (N % 128 == 0)
      gload16((const char*)Bw + (size_t)nr * rowb + kt * 128 + lslot,
              (char*)&B_lds[b][0] + c * 1024);
    }
  };

  stage(0, 0);
  __syncthreads();

  for (int kt = 0; kt < kT; ++kt) {
    const int cur = kt & 1;
    if (kt + 1 < kT) stage(kt + 1, cur ^ 1);        // prefetch next tile, other buffer
#pragma unroll
    for (int ks = 0; ks < 2; ++ks) {
      bf16x8 af[4], bfr[4];
      const int cb = (ks * 64 + lg * 16) ^ rswz;    // swizzled read slot
#pragma unroll
      for (int i = 0; i < 4; ++i) {
        af[i]  = *reinterpret_cast<const bf16x8*>(
                   (const char*)&A_lds[cur][0] + (wm + i * 16 + lr) * 128 + cb);
        bfr[i] = *reinterpret_cast<const bf16x8*>(
                   (const char*)&B_lds[cur][0] + (wn + i * 16 + lr) * 128 + cb);
      }
      __builtin_amdgcn_s_setprio(1);
#pragma unroll
      for (int mi = 0; mi < 4; ++mi)
#pragma unroll
        for (int ni = 0; ni < 4; ++ni)
          acc[mi][ni] = mfma16(af[mi], bfr[ni], acc[mi][ni]);
      __builtin_amdgcn_s_setprio(0);
    }
    __syncthreads();   // drains this iter's prefetch (issued ~2 MFMA phases ago)
  }

  // epilogue: C row = m0+wm+mi*16+lg*4+r, col = n0+wn+ni*16+lr
#pragma unroll
  for (int mi = 0; mi < 4; ++mi) {
#pragma unroll
    for (int r = 0; r < 4; ++r) {
      int gm = m0 + wm + mi * 16 + lg * 4 + r;
      if (gm >= Mdim) continue;
#pragma unroll
      for (int ni = 0; ni < 4; ++ni) {
        int gn = n0 + wn + ni * 16 + lr;
        float v = acc[mi][ni][r];
        if (MODE == 0) {
          ((unsigned short*)outp)[(size_t)gm * N + gn] = f2bf(v);
        } else if (MODE == 1) {
          int b = gm / S_, s = gm - b * S_;
          int hh = gn >> 7, d = gn & 127;
          ((unsigned short*)outp)[(((size_t)(b * H_ + hh) * S_ + s) << 7) + d] = f2bf(v);
        } else if (MODE == 2) {
          float g = bf2f(gin[(size_t)gm * N + gn]);
          float sg = g / (1.f + __expf(-g));
          ((unsigned short*)outp)[(size_t)gm * N + gn] = f2bf(sg * v);
        } else {
          ((float*)outp)[(size_t)gm * N + gn] += v;
        }
      }
    }
  }
}

// ---------------- rope apply (in-place, q & k) ----------------
__global__ __launch_bounds__(256) void rope_apply(unsigned short* __restrict__ qb,
    unsigned short* __restrict__ kb, const float* __restrict__ cosT,
    const float* __restrict__ sinT) {
  size_t i = (size_t)blockIdx.x * 256 + threadIdx.x;  // B*H*S*64 slots
  int d = (int)(i & 63);
  size_t row = i >> 6;              // (b*H+h)*S + s
  int s = (int)(row % S_);
  size_t base = row * DH_;
  float c = cosT[s * DH_ + d], sn = sinT[s * DH_ + d];
  float q0 = bf2f(qb[base + d]), q1 = bf2f(qb[base + d + 64]);
  qb[base + d]      = f2bf(q0 * c - q1 * sn);
  qb[base + d + 64] = f2bf(q1 * c + q0 * sn);
  float k0 = bf2f(kb[base + d]), k1 = bf2f(kb[base + d + 64]);
  kb[base + d]      = f2bf(k0 * c - k1 * sn);
  kb[base + d + 64] = f2bf(k1 * c + k0 * sn);
}

// ---------------- V transpose: vb [b][h][s][128] -> vt [bh][128][1024] ----------------
__global__ __launch_bounds__(256) void vtrans_k(const unsigned short* __restrict__ vb,
    unsigned short* __restrict__ vt) {
  __shared__ unsigned int tile[64][33];
  const int t = threadIdx.x;
  const int s0 = blockIdx.x * 64, d0 = blockIdx.y * 64, bh = blockIdx.z;
#pragma unroll
  for (int j = 0; j < 2; ++j) {
    int idx = t + 256 * j;
    int s_r = idx >> 3, c8 = (idx & 7) << 3;
    int srow = s0 + s_r; srow = srow < S_ ? srow : S_ - 1;
    int4 v = *reinterpret_cast<const int4*>(&vb[((size_t)bh * S_ + srow) * DH_ + d0 + c8]);
    tile[s_r][(c8 >> 1) + 0] = (unsigned)v.x;
    tile[s_r][(c8 >> 1) + 1] = (unsigned)v.y;
    tile[s_r][(c8 >> 1) + 2] = (unsigned)v.z;
    tile[s_r][(c8 >> 1) + 3] = (unsigned)v.w;
  }
  __syncthreads();
#pragma unroll
  for (int j = 0; j < 2; ++j) {
    int idx = t + 256 * j;
    int d_r = idx >> 3, s8 = (idx & 7) << 3;
    unsigned r[8];
#pragma unroll
    for (int e = 0; e < 8; ++e) {
      unsigned wv = tile[s8 + e][d_r >> 1];
      r[e] = (d_r & 1) ? (wv >> 16) : (wv & 0xffffu);
    }
    int4 ov;
    ov.x = (int)(r[0] | (r[1] << 16));
    ov.y = (int)(r[2] | (r[3] << 16));
    ov.z = (int)(r[4] | (r[5] << 16));
    ov.w = (int)(r[6] | (r[7] << 16));
    *reinterpret_cast<int4*>(&vt[((size_t)(bh * 128 + d0 + d_r)) * 1024 + s0 + s8]) = ov;
  }
}

// ---------------- causal flash attention v2 (swapped-QK, 8 waves, 128 q rows) --------
__global__ __launch_bounds__(512, 4) void attn2_k(const unsigned short* __restrict__ qg,
    const unsigned short* __restrict__ kg, const unsigned short* __restrict__ vtg,
    unsigned short* __restrict__ ctx) {
  __shared__ unsigned short K_lds[64 * 128];
  __shared__ unsigned short VT_lds[128 * 64];
  const int t = threadIdx.x, lane = t & 63, w = t >> 6;
  const int lr = lane & 15, lg = lane >> 4;
  const int bh = blockIdx.x, qt = blockIdx.y;
  const int q0 = qt * 128;
  const int b = bh >> 4, hh = bh & 15;
  const size_t kbase2 = (size_t)bh * S_ * DH_ * 2;   // byte base of this head
  const int q_idx = q0 + w * 16 + lr;
  const int swz = (lr & 7) << 4;

  bf16x8 qf[4];
#pragma unroll
  for (int ks = 0; ks < 4; ++ks) {
    bf16x8 z;
#pragma unroll
    for (int e = 0; e < 8; ++e) z[e] = 0;
    if (q_idx < S_)
      z = *reinterpret_cast<const bf16x8*>(
            (const char*)qg + kbase2 + (size_t)q_idx * 256 + ks * 64 + lg * 16);
    qf[ks] = z;
  }
  float mst = -1e30f, lst = 0.f;
  f32x4 cacc[8];
#pragma unroll
  for (int f = 0; f < 8; ++f) cacc[f] = zero4();

  const int q_hi = (q0 + 127 < S_) ? q0 + 127 : S_ - 1;
  const int nt = q_hi / 64 + 1;
  const int wq_max = q0 + w * 16 + 15;

  for (int kt = 0; kt < nt; ++kt) {
    const int kv0 = kt * 64;
    __syncthreads();
    // stage K [64][128] and VT [128][64], XOR-swizzled source -> linear LDS
#pragma unroll
    for (int j = 0; j < 2; ++j) {
      const int chunk = w + 8 * j;            // 0..15, 1024B each
      int krow = chunk * 4 + (lane >> 4);     // 4 rows x 256B
      int kcolb = (lane & 15) << 4;
      int gr = kv0 + krow; gr = gr < S_ ? gr : S_ - 1;
      gload16((const char*)kg + kbase2 + (size_t)gr * 256 + (kcolb ^ ((krow & 7) << 4)),
              (char*)K_lds + chunk * 1024);
      int vrow = chunk * 8 + (lane >> 3);     // 8 rows x 128B
      int vcolb = (lane & 7) << 4;
      gload16((const char*)vtg + ((size_t)(bh * 128 + vrow) * 1024 + kv0) * 2 + (vcolb ^ ((vrow & 7) << 4)),
              (char*)VT_lds + chunk * 1024);
    }
    __syncthreads();
    if (kv0 > wq_max) continue;               // whole wave masked this tile

    // S^T = K . Q^T  (row = kv, col = q = lr)
    f32x4 sacc[4];
#pragma unroll
    for (int c = 0; c < 4; ++c) sacc[c] = zero4();
#pragma unroll
    for (int ks = 0; ks < 4; ++ks) {
#pragma unroll
      for (int c = 0; c < 4; ++c) {
        bf16x8 kf = *reinterpret_cast<const bf16x8*>(
            &K_lds[(c * 16 + lr) * 128 + (((ks * 64 + lg * 16) ^ swz) >> 1)]);
        sacc[c] = mfma16(kf, qf[ks], sacc[c]);
      }
    }
    // mask + online softmax (per-lane scalar m/l; reduce across lg groups)
    float p[4][4];
    float mx = -1e30f;
#pragma unroll
    for (int c = 0; c < 4; ++c)
#pragma unroll
      for (int r = 0; r < 4; ++r) {
        int kv = kv0 + c * 16 + lg * 4 + r;
        float v = sacc[c][r] * 0.08838834764831845f;   // 1/sqrt(128)
        if (kv > q_idx || kv >= S_) v = -1e30f;
        p[c][r] = v;
        mx = fmaxf(mx, v);
      }
    mx = fmaxf(mx, __shfl_xor(mx, 16));
    mx = fmaxf(mx, __shfl_xor(mx, 32));
    float mn = fmaxf(mst, mx);
    float corr = __expf(mst - mn);
    mst = mn;
    float rs = 0.f;
#pragma unroll
    for (int c = 0; c < 4; ++c)
#pragma unroll
      for (int r = 0; r < 4; ++r) {
        float e = __expf(p[c][r] - mn);
        p[c][r] = e;
        rs += e;
      }
    rs += __shfl_xor(rs, 16);
    rs += __shfl_xor(rs, 32);
    lst = lst * corr + rs;
#pragma unroll
    for (int f = 0; f < 8; ++f)
#pragma unroll
      for (int r = 0; r < 4; ++r) cacc[f][r] *= corr;

    // pack P (bf16 pairs) and redistribute to PV B-operand via shfl
    unsigned pk01[4], pk23[4];
#pragma unroll
    for (int c = 0; c < 4; ++c) {
      pk01[c] = (unsigned)f2bf(p[c][0]) | ((unsigned)f2bf(p[c][1]) << 16);
      pk23[c] = (unsigned)f2bf(p[c][2]) | ((unsigned)f2bf(p[c][3]) << 16);
    }
#pragma unroll
    for (int ks = 0; ks < 2; ++ks) {
      unsigned bu[4];
#pragma unroll
      for (int jj = 0; jj < 4; ++jj) {
        const int srcl = ((lg & 1) * 2 + (jj >> 1)) * 16 + lr;
        unsigned lo = (unsigned)__shfl((int)((jj & 1) ? pk23[2 * ks]     : pk01[2 * ks]),     srcl);
        unsigned hi = (unsigned)__shfl((int)((jj & 1) ? pk23[2 * ks + 1] : pk01[2 * ks + 1]), srcl);
        bu[jj] = (lg >= 2) ? hi : lo;
      }
      union { unsigned u[4]; bf16x8 v; } pb;
      pb.u[0] = bu[0]; pb.u[1] = bu[1]; pb.u[2] = bu[2]; pb.u[3] = bu[3];
#pragma unroll
      for (int f = 0; f < 8; ++f) {
        bf16x8 vtf = *reinterpret_cast<const bf16x8*>(
            &VT_lds[(f * 16 + lr) * 64 + (((ks * 64 + lg * 16) ^ swz) >> 1)]);
        cacc[f] = mfma16(vtf, pb.v, cacc[f]);
      }
    }
  }

  // O^T frag: col = q = lr, row = d = f*16 + lg*4 + r  -> packed 8B stores
  if (q_idx < S_) {
    float inv = 1.f / lst;
    unsigned short* cp = ctx + ((size_t)(b * S_ + q_idx)) * D_ + hh * 128;
#pragma unroll
    for (int f = 0; f < 8; ++f) {
      unsigned lo = (unsigned)f2bf(cacc[f][0] * inv) | ((unsigned)f2bf(cacc[f][1] * inv) << 16);
      unsigned hi = (unsigned)f2bf(cacc[f][2] * inv) | ((unsigned)f2bf(cacc[f][3] * inv) << 16);
      uint2 ov; ov.x = lo; ov.y = hi;
      *reinterpret_cast<uint2*>(cp + f * 16 + lg * 4) = ov;
    }
  }
}

// ---------------- mean pool over sequence ----------------
__global__ __launch_bounds__(256) void meanpool(const unsigned short* __restrict__ xn,
    float* __restrict__ out) {
  int d = blockIdx.x * 256 + threadIdx.x;
  int b = blockIdx.y;
  const unsigned short* p = xn + (size_t)b * S_ * D_ + d;
  float s = 0.f;
  for (int i = 0; i < S_; ++i) s += bf2f(p[(size_t)i * D_]);
  out[(size_t)b * D_ + d] = s * (1.f / S_);
}

// ---------------- series branch: adds into out ----------------
__global__ __launch_bounds__(256) void series_k(const float* __restrict__ x,
    const float* __restrict__ pw, const float* __restrict__ pb, float* out) {
  __shared__ float sm[T_];
  __shared__ float emb[D_];
  __shared__ float red[4];
  int b = blockIdx.x, t = threadIdx.x;
  if (t < T_) {
    float s = 0.f;
    for (int c = 0; c < C_; ++c) s += x[((size_t)b * C_ + c) * T_ + t];
    sm[t] = s * (1.f / C_);
  }
  __syncthreads();
  float ssq = 0.f;
#pragma unroll
  for (int j = 0; j < D_ / 256; ++j) {
    int d = j * 256 + t;
    float e = pb[d];
    for (int tt = 0; tt < T_; ++tt) e += sm[tt] * pw[(size_t)d * T_ + tt];
    emb[d] = e;
    ssq += e * e;
  }
#pragma unroll
  for (int m = 1; m < 64; m <<= 1) ssq += __shfl_xor(ssq, m);
  if ((t & 63) == 0) red[t >> 6] = ssq;
  __syncthreads();
  float tot = red[0] + red[1] + red[2] + red[3];
  float inv = 1.f / fmaxf(sqrtf(tot), 1e-12f);
#pragma unroll
  for (int j = 0; j < D_ / 256; ++j) {
    int d = j * 256 + t;
    out[(size_t)b * D_ + d] += emb[d] * inv;
  }
}

extern "C" void kernel_launch(void* const* d_in, const int* in_sizes, int n_in,
                              void* d_out, int out_size, void* d_ws, size_t ws_size,
                              hipStream_t stream) {
  const float* x      = (const float*)d_in[0];
  const int*   tok    = (const int*)d_in[1];
  const float* embedw = (const float*)d_in[2];
  const int*   wq_idx = (const int*)d_in[3];
  const float* wq_sc  = (const float*)d_in[4];
  const int*   wk_idx = (const int*)d_in[5];
  const float* wk_sc  = (const float*)d_in[6];
  const int*   wv_idx = (const int*)d_in[7];
  const float* wv_sc  = (const float*)d_in[8];
  const int*   wo_idx = (const int*)d_in[9];
  const float* wo_sc  = (const float*)d_in[10];
  const int*   wg_idx = (const int*)d_in[11];
  const float* wg_sc  = (const float*)d_in[12];
  const int*   wu_idx = (const int*)d_in[13];
  const float* wu_sc  = (const float*)d_in[14];
  const int*   wd_idx = (const int*)d_in[15];
  const float* wd_sc  = (const float*)d_in[16];
  const float* ln1    = (const float*)d_in[17];
  const float* ln2    = (const float*)d_in[18];
  const float* lnf    = (const float*)d_in[19];
  const float* projw  = (const float*)d_in[20];
  const float* projb  = (const float*)d_in[21];
  float* out = (float*)d_out;
  (void)in_sizes; (void)n_in; (void)out_size; (void)ws_size;

  char* wsp = (char*)d_ws;
  size_t off = 0;
  auto alloc = [&](size_t bytes) -> void* {
    void* p = wsp + off; off += (bytes + 255) & ~(size_t)255; return p; };
  float* cosT = (float*)alloc((size_t)S_ * DH_ * 4);
  float* sinT = (float*)alloc((size_t)S_ * DH_ * 4);
  float* hbuf = (float*)alloc((size_t)M_ * D_ * 4);
  unsigned short* xn  = (unsigned short*)alloc((size_t)M_ * D_ * 2);
  unsigned short* qb  = (unsigned short*)alloc((size_t)B_ * H_ * S_ * DH_ * 2);
  unsigned short* kb  = (unsigned short*)alloc((size_t)B_ * H_ * S_ * DH_ * 2);
  unsigned short* vb  = (unsigned short*)alloc((size_t)B_ * H_ * S_ * DH_ * 2);
  unsigned short* wdeq = (unsigned short*)alloc((size_t)DFF_ * D_ * 2);  // 22.5 MB
  unsigned short* ctx = xn;     // alias: xn dead during attention, rewritten after O-GEMM
  unsigned short* gbuf = qb;    // alias: 44MB g/act spans q+k+v (49MB), dead during MLP
  unsigned short* vt  = wdeq;   // alias: V^T [bh][128][1024] (16.8MB), dead before O-dequant

  rope_tables<<<S_, DH_, 0, stream>>>(cosT, sinT);
  embed_gather<<<M_, 256, 0, stream>>>(tok, embedw, hbuf);

  const int nxAtt = D_ / 128;                 // 16
  const int nxMlp = DFF_ / 128;               // 43
  const int my = (M_ + 127) / 128;            // 32
  const dim3 gAtt(nxAtt * my);                // 512 blocks
  const dim3 gMlp(nxMlp * my);                // 1376 blocks
  const dim3 dqD(1, D_), dqF(1, DFF_), dqK(3, D_);  // dequant grids

  for (int l = 0; l < L_N; ++l) {
    const int*   wqi = wq_idx + (size_t)l * D_ * D_;
    const float* wqs = wq_sc + (size_t)l * D_ * (D_ / 64);
    const int*   wki = wk_idx + (size_t)l * D_ * D_;
    const float* wks = wk_sc + (size_t)l * D_ * (D_ / 64);
    const int*   wvi = wv_idx + (size_t)l * D_ * D_;
    const float* wvs = wv_sc + (size_t)l * D_ * (D_ / 64);
    const int*   woi = wo_idx + (size_t)l * D_ * D_;
    const float* wos = wo_sc + (size_t)l * D_ * (D_ / 64);
    const int*   wgi = wg_idx + (size_t)l * DFF_ * D_;
    const float* wgs = wg_sc + (size_t)l * DFF_ * (D_ / 64);
    const int*   wui = wu_idx + (size_t)l * DFF_ * D_;
    const float* wus = wu_sc + (size_t)l * DFF_ * (D_ / 64);
    const int*   wdi = wd_idx + (size_t)l * D_ * DFF_;
    const float* wds = wd_sc + (size_t)l * D_ * (DFF_ / 64);

    rmsnorm_k<<<M_, 256, 0, stream>>>(hbuf, ln1 + l * D_, xn);
    dequant_k<<<dqD, 256, 0, stream>>>(wqi, wqs, wdeq, D_);
    gemm_bf16<1><<<gAtt, 256, 0, stream>>>(xn, wdeq, M_, D_, D_, nxAtt, qb, nullptr);
    dequant_k<<<dqD, 256, 0, stream>>>(wki, wks, wdeq, D_);
    gemm_bf16<1><<<gAtt, 256, 0, stream>>>(xn, wdeq, M_, D_, D_, nxAtt, kb, nullptr);
    dequant_k<<<dqD, 256, 0, stream>>>(wvi, wvs, wdeq, D_);
    gemm_bf16<1><<<gAtt, 256, 0, stream>>>(xn, wdeq, M_, D_, D_, nxAtt, vb, nullptr);
    rope_apply<<<(B_ * H_ * S_ * 64) / 256, 256, 0, stream>>>(qb, kb, cosT, sinT);
    vtrans_k<<<dim3(16, 2, B_ * H_), 256, 0, stream>>>(vb, vt);
    attn2_k<<<dim3(B_ * H_, 8), 512, 0, stream>>>(qb, kb, vt, ctx);
    dequant_k<<<dqD, 256, 0, stream>>>(woi, wos, wdeq, D_);
    gemm_bf16<3><<<gAtt, 256, 0, stream>>>(ctx, wdeq, M_, D_, D_, nxAtt, hbuf, nullptr);
    rmsnorm_k<<<M_, 256, 0, stream>>>(hbuf, ln2 + l * D_, xn);
    dequant_k<<<dqF, 256, 0, stream>>>(wgi, wgs, wdeq, D_);
    gemm_bf16<0><<<gMlp, 256, 0, stream>>>(xn, wdeq, M_, DFF_, D_, nxMlp, gbuf, nullptr);
    dequant_k<<<dqF, 256, 0, stream>>>(wui, wus, wdeq, D_);
    gemm_bf16<2><<<gMlp, 256, 0, stream>>>(xn, wdeq, M_, DFF_, D_, nxMlp, gbuf, gbuf);
    dequant_k<<<dqK, 256, 0, stream>>>(wdi, wds, wdeq, DFF_);
    gemm_bf16<3><<<gAtt, 256, 0, stream>>>(gbuf, wdeq, M_, D_, DFF_, nxAtt, hbuf, nullptr);
  }

  rmsnorm_k<<<M_, 256, 0, stream>>>(hbuf, lnf, xn);
  meanpool<<<dim3(D_ / 256, B_), 256, 0, stream>>>(xn, out);
  series_k<<<B_, 256, 0, stream>>>(x, projw, projb, out);
}